// Round 8
// baseline (235.266 us; speedup 1.0000x reference)
//
#include <hip/hip_runtime.h>
#include <math.h>

#define BATCH   8
#define SEQ     4096
#define DMODEL  256
#define DINNER  512
#define DSTATE  64
#define NHEADS  8
#define HEADDIM 64
#define CONVDIM 640          // DINNER + 2*DSTATE
#define DPROJ   1160         // 2*DINNER + 2*DSTATE + NHEADS
#define NROWS   (BATCH*SEQ)  // 32768
#define CHUNK   64
#define NCHUNK  (SEQ/CHUNK)  // 64
#define NPAD    1280         // DPROJ padded to mult of 128 for bf16 W_in
#define LSTR    72           // LDS row stride (shorts)

typedef short bf16x8 __attribute__((ext_vector_type(8)));
typedef short short8v __attribute__((ext_vector_type(8)));
typedef float f32x4 __attribute__((ext_vector_type(4)));

// ---- static workspace (BSS) ----
__device__ short g_xn[(size_t)NROWS * DMODEL];      // bf16 16.8 MB
__device__ short g_zxb[(size_t)NROWS * DPROJ];      // bf16 76.0 MB (z | xBC | unused dt)
__device__ short g_xbc[(size_t)NROWS * CONVDIM];    // bf16 42.0 MB (conv out; x-slice later overwritten by y)
__device__ float g_dt[(size_t)NROWS * NHEADS];      // fp32  1.0 MB (raw dt, pre-bias)
__device__ short g_yzn[(size_t)NROWS * DINNER];     // bf16 33.5 MB
__device__ short g_lstate[(size_t)BATCH * NHEADS * NCHUNK * HEADDIM * DSTATE]; // bf16 33.5 MB
__device__ float g_decayC[BATCH * NHEADS * NCHUNK];
__device__ short g_Winb[(size_t)NPAD * DMODEL];     // bf16 W_in, zero-padded rows
__device__ short g_Woutb[(size_t)DMODEL * DINNER];  // bf16 W_out

__device__ __forceinline__ short f2bf(float f) {
    unsigned u = __float_as_uint(f);
    u += 0x7fff + ((u >> 16) & 1);
    return (short)(u >> 16);
}
__device__ __forceinline__ float bf2f(short s) {
    return __uint_as_float(((unsigned)(unsigned short)s) << 16);
}

__device__ __forceinline__ void stage16(const void* gsrc, void* ldst) {
    __builtin_amdgcn_global_load_lds(
        (const __attribute__((address_space(1))) void*)gsrc,
        (__attribute__((address_space(3))) void*)ldst, 16, 0, 0);
}

// ---------------- weight convert: fp32 -> bf16 with flat zero-pad tail ----------------
__global__ __launch_bounds__(256) void convert_bf16_kernel(const float* __restrict__ src,
                                                           short* __restrict__ dst,
                                                           int n_valid, int n_total) {
    const int i = blockIdx.x * 256 + threadIdx.x;
    if (i < n_total) dst[i] = (i < n_valid) ? f2bf(src[i]) : (short)0;
}

// ---------------- rmsnorm of x (D=256) -> bf16 xn AND exact fp32 dt (8 heads) ----------
__global__ __launch_bounds__(256) void rmsnorm_dt_kernel(const float* __restrict__ x,
                                                         const float* __restrict__ w,
                                                         const float* __restrict__ W_in,
                                                         short* __restrict__ xn,
                                                         float* __restrict__ dt) {
    const int row  = blockIdx.x * 4 + (threadIdx.x >> 6);
    const int lane = threadIdx.x & 63;
    const float4 v = *(const float4*)(x + (size_t)row * DMODEL + lane * 4);
    float ss = v.x * v.x + v.y * v.y + v.z * v.z + v.w * v.w;
#pragma unroll
    for (int off = 1; off < 64; off <<= 1) ss += __shfl_xor(ss, off);
    const float rs = rsqrtf(ss * (1.0f / DMODEL) + 1.1920929e-7f);
    const float4 wv = *(const float4*)(w + lane * 4);
    const float4 xn4 = make_float4(v.x * rs * wv.x, v.y * rs * wv.y,
                                   v.z * rs * wv.z, v.w * rs * wv.w);
    short4 o;
    o.x = f2bf(xn4.x); o.y = f2bf(xn4.y); o.z = f2bf(xn4.z); o.w = f2bf(xn4.w);
    *(short4*)(xn + (size_t)row * DMODEL + lane * 4) = o;
#pragma unroll
    for (int h = 0; h < NHEADS; ++h) {
        const float4 ww = *(const float4*)(W_in + (size_t)(DPROJ - NHEADS + h) * DMODEL + lane * 4);
        float p = xn4.x * ww.x + xn4.y * ww.y + xn4.z * ww.z + xn4.w * ww.w;
#pragma unroll
        for (int off = 1; off < 64; off <<= 1) p += __shfl_xor(p, off);
        if (lane == 0) dt[(size_t)row * NHEADS + h] = p;
    }
}

// ---------------- bf16 MFMA GEMM: C[M][N] = A[M][K] * B[N][K]^T ----------
// XCD-chunked 1-D grid swizzle (round 7). NEW: LDS-transpose epilogue — each
// wave dumps its 64x64 acc tile to LDS, then all threads store contiguous
// 16B chunks (and read the residual as float4). Replaces 64 scalar stores.
template <bool RES, typename OUT>
__global__ __launch_bounds__(256) void gemm_bf16_nt(const short* __restrict__ A,
                                                    const short* __restrict__ B,
                                                    const float* __restrict__ R,
                                                    OUT* __restrict__ C,
                                                    int NX, int M, int N, int K) {
    const int L   = blockIdx.x;
    const int xcd = L & 7;
    const int r   = L >> 3;
    const int mstrips_per_xcd = (M / 128) >> 3;
    const int mblk = xcd * mstrips_per_xcd + r / NX;
    const int nblk = r % NX;
    const int m0 = mblk * 128, n0 = nblk * 128;

    // unified LDS: staging (16 KB) overlaid with transpose buffer
    constexpr int RSE = (sizeof(OUT) == 2) ? 132 : 130;       // row stride (elems)
    constexpr size_t TB = (size_t)64 * RSE * sizeof(OUT);
    constexpr size_t SB = (TB > 32768) ? TB : 32768;
    __shared__ __align__(16) char smem[SB];
    short* Asl = (short*)smem;
    short* Bsl = (short*)smem + 4096;
    OUT* buf = (OUT*)smem;

    const int tid  = threadIdx.x;
    const int lane = tid & 63;
    const int wid  = tid >> 6;
    const int wrow = (wid >> 1) * 64, wcol = (wid & 1) * 64;

    f32x4 acc[4][4];
#pragma unroll
    for (int m = 0; m < 4; ++m)
#pragma unroll
        for (int n = 0; n < 4; ++n) acc[m][n] = (f32x4)0.f;

    const int wbase = (tid & 0xC0) * 8;

    for (int k0 = 0; k0 < K; k0 += 32) {
#pragma unroll
        for (int rr = 0; rr < 2; ++rr) {
            const int idx = rr * 256 + tid;
            const int row = idx >> 2;
            const int ko  = (idx & 3) * 8;
            stage16(A + (size_t)(m0 + row) * K + k0 + ko, Asl + rr * 2048 + wbase);
            stage16(B + (size_t)(n0 + row) * K + k0 + ko, Bsl + rr * 2048 + wbase);
        }
        __syncthreads();
        bf16x8 af[4], bfr[4];
#pragma unroll
        for (int m = 0; m < 4; ++m)
            af[m] = *(const bf16x8*)(Asl + (wrow + m * 16 + (lane & 15)) * 32 + (lane >> 4) * 8);
#pragma unroll
        for (int n = 0; n < 4; ++n)
            bfr[n] = *(const bf16x8*)(Bsl + (wcol + n * 16 + (lane & 15)) * 32 + (lane >> 4) * 8);
#pragma unroll
        for (int m = 0; m < 4; ++m)
#pragma unroll
            for (int n = 0; n < 4; ++n)
                acc[m][n] = __builtin_amdgcn_mfma_f32_16x16x32_bf16(af[m], bfr[n], acc[m][n], 0, 0, 0);
        __syncthreads();
    }

    // ---- LDS-transpose epilogue, two row-phases (waves 0,1 then 2,3) ----
#pragma unroll
    for (int phase = 0; phase < 2; ++phase) {
        if ((wid >> 1) == phase) {
#pragma unroll
            for (int m = 0; m < 4; ++m)
#pragma unroll
                for (int n = 0; n < 4; ++n)
#pragma unroll
                    for (int reg = 0; reg < 4; ++reg) {
                        const int row = m * 16 + (lane >> 4) * 4 + reg;   // 0..63
                        const int col = wcol + n * 16 + (lane & 15);      // 0..127
                        if constexpr (sizeof(OUT) == 2)
                            buf[row * RSE + col] = f2bf(acc[m][n][reg]);
                        else
                            buf[row * RSE + col] = acc[m][n][reg];
                    }
        }
        __syncthreads();
        if constexpr (sizeof(OUT) == 2) {
#pragma unroll
            for (int q = 0; q < 4; ++q) {
                const int idx  = q * 256 + tid;
                const int row  = idx >> 4;
                const int coff = (idx & 15) * 8;
                const int grow = m0 + phase * 64 + row;
                const int gcol = n0 + coff;
                if (gcol < N)
                    *(short8v*)(C + (size_t)grow * N + gcol) =
                        *(const short8v*)(buf + row * RSE + coff);
            }
        } else {
#pragma unroll
            for (int q = 0; q < 8; ++q) {
                const int idx  = q * 256 + tid;
                const int row  = idx >> 5;
                const int coff = (idx & 31) * 4;
                const int grow = m0 + phase * 64 + row;
                const int gcol = n0 + coff;
                if (gcol < N) {
                    f32x4 v = *(const f32x4*)(buf + row * RSE + coff);
                    if (RES) {
                        const f32x4 rv = *(const f32x4*)(R + (size_t)grow * N + gcol);
                        v += rv;
                    }
                    *(f32x4*)(C + (size_t)grow * N + gcol) = v;
                }
            }
        }
        if (phase == 0) __syncthreads();
    }
}

// ---- depthwise causal conv(4) + bias + SiLU: sliding window, 4 rows x 8 ch per thread ----
__global__ __launch_bounds__(256) void conv_silu_kernel(const short* __restrict__ zxb,
                                                        const float* __restrict__ cw,
                                                        const float* __restrict__ cb,
                                                        short* __restrict__ xbc) {
    const int idx = blockIdx.x * 256 + threadIdx.x;   // over (NROWS/4)*80
    const int c8  = (idx % 80) * 8;
    const int bl0 = (idx / 80) * 4;                   // first of 4 rows
    const int l0  = bl0 & (SEQ - 1);
    const short* src = zxb + (size_t)bl0 * DPROJ + DINNER + c8;

    float4 w4[8];
    float bias[8];
#pragma unroll
    for (int j = 0; j < 8; ++j) w4[j] = *(const float4*)(cw + (c8 + j) * 4);
    {
        const float4 b0 = *(const float4*)(cb + c8);
        const float4 b1 = *(const float4*)(cb + c8 + 4);
        bias[0] = b0.x; bias[1] = b0.y; bias[2] = b0.z; bias[3] = b0.w;
        bias[4] = b1.x; bias[5] = b1.y; bias[6] = b1.z; bias[7] = b1.w;
    }

    bf16x8 rowv[7];                                   // rows l0-3 .. l0+3
#pragma unroll
    for (int m = 0; m < 7; ++m) {
        if (l0 + m - 3 >= 0)
            rowv[m] = *(const bf16x8*)(src + (ptrdiff_t)(m - 3) * DPROJ);
        else
            rowv[m] = (bf16x8)0;
    }

#pragma unroll
    for (int r = 0; r < 4; ++r) {
        float acc[8];
#pragma unroll
        for (int j = 0; j < 8; ++j) acc[j] = bias[j];
#pragma unroll
        for (int k = 0; k < 4; ++k) {
            const bf16x8 tap = rowv[r + k];
#pragma unroll
            for (int j = 0; j < 8; ++j)
                acc[j] = fmaf(bf2f(tap[j]), ((const float*)&w4[j])[k], acc[j]);
        }
        short8v o;
#pragma unroll
        for (int j = 0; j < 8; ++j) {
            const float s = acc[j];
            o[j] = f2bf(s / (1.f + __expf(-s)));
        }
        *(short8v*)(xbc + (size_t)(bl0 + r) * CONVDIM + c8) = o;
    }
}

// ---------------- scan pass 1 (MFMA): L[p][n] = sum_t X[t][p] * (w_t * B[t][n]) ----------
__global__ __launch_bounds__(256) void chunk_state_mfma(const float* __restrict__ dt,
                                                        const short* __restrict__ xbc,
                                                        const float* __restrict__ dt_bias,
                                                        const float* __restrict__ A_log,
                                                        short* __restrict__ lstate,
                                                        float* __restrict__ decayC) {
    const int bhc = blockIdx.x;
    const int c = bhc & (NCHUNK - 1), bh = bhc >> 6, h = bh & (NHEADS - 1), b = bh >> 3;
    const int tid = threadIdx.x, lane = tid & 63, wid = tid >> 6;
    __shared__ short XT[64 * LSTR];   // XT[p][t]
    __shared__ short BT[64 * LSTR];   // (w*B)^T [n][t]
    __shared__ float wsh[CHUNK];
    const size_t row0 = (size_t)b * SEQ + (size_t)c * CHUNK;

    const float aneg  = -__expf(A_log[h]);
    const float dbias = dt_bias[h];
    if (tid < 64) {
        const float draw = dt[(row0 + tid) * NHEADS + h] + dbias;
        const float dtv  = (draw > 20.f) ? draw : log1pf(__expf(draw));
        float cum = aneg * dtv;
#pragma unroll
        for (int off = 1; off < 64; off <<= 1) {
            const float nv = __shfl_up(cum, off);
            if (lane >= off) cum += nv;
        }
        const float total = __shfl(cum, 63);
        wsh[tid] = __expf(total - cum) * dtv;
        if (tid == 63) decayC[bhc] = __expf(cum);
    }
    __syncthreads();

#pragma unroll
    for (int r = 0; r < 4; ++r) {
        const int idx  = tid + r * 256;
        const int trow = idx >> 4;
        const int c4   = (idx & 15) * 4;
        const short* rp = xbc + (row0 + trow) * CONVDIM;
        const short4 xv = *(const short4*)(rp + h * 64 + c4);
        const short4 bv = *(const short4*)(rp + DINNER + c4);
        const float w = wsh[trow];
        XT[(c4 + 0) * LSTR + trow] = xv.x;
        XT[(c4 + 1) * LSTR + trow] = xv.y;
        XT[(c4 + 2) * LSTR + trow] = xv.z;
        XT[(c4 + 3) * LSTR + trow] = xv.w;
        BT[(c4 + 0) * LSTR + trow] = f2bf(bf2f(bv.x) * w);
        BT[(c4 + 1) * LSTR + trow] = f2bf(bf2f(bv.y) * w);
        BT[(c4 + 2) * LSTR + trow] = f2bf(bf2f(bv.z) * w);
        BT[(c4 + 3) * LSTR + trow] = f2bf(bf2f(bv.w) * w);
    }
    __syncthreads();

    f32x4 acc[4];
#pragma unroll
    for (int n = 0; n < 4; ++n) acc[n] = (f32x4)0.f;
#pragma unroll
    for (int ks = 0; ks < 2; ++ks) {
        const bf16x8 af = *(const bf16x8*)(XT + (wid * 16 + (lane & 15)) * LSTR + ks * 32 + (lane >> 4) * 8);
#pragma unroll
        for (int n = 0; n < 4; ++n) {
            const bf16x8 bfv = *(const bf16x8*)(BT + (n * 16 + (lane & 15)) * LSTR + ks * 32 + (lane >> 4) * 8);
            acc[n] = __builtin_amdgcn_mfma_f32_16x16x32_bf16(af, bfv, acc[n], 0, 0, 0);
        }
    }
    short* lp = lstate + ((size_t)bhc << 12);
#pragma unroll
    for (int n = 0; n < 4; ++n)
#pragma unroll
        for (int reg = 0; reg < 4; ++reg) {
            const int p = wid * 16 + (lane >> 4) * 4 + reg;
            lp[p * 64 + n * 16 + (lane & 15)] = f2bf(acc[n][reg]);
        }
}

// ---------------- scan pass 2: inter-chunk recurrence (bf16 lstate, fp32 carry) --------
__global__ __launch_bounds__(256) void state_prefix_kernel(short* __restrict__ lstate,
                                                           const float* __restrict__ decayC) {
    const int idx = blockIdx.x * 256 + threadIdx.x;   // over BATCH*NHEADS*4096
    const int bh = idx >> 12;
    const int pn = idx & 4095;
    float S = 0.f;
    for (int c = 0; c < NCHUNK; ++c) {
        short* ptr = lstate + (((size_t)bh * NCHUNK + c) << 12) + pn;
        const float l = bf2f(*ptr);
        *ptr = f2bf(S);
        S = fmaf(S, decayC[bh * NCHUNK + c], l);
    }
}

// ---- scan pass 3 (MFMA): Y = mask(C@B^T)@X + exp(cum)*(C@SP^T) + Dp*X; y (bf16) in place --
__global__ __launch_bounds__(256) void chunk_scan_mfma(const float* __restrict__ dt,
                                                       short* __restrict__ xbc,
                                                       const float* __restrict__ dt_bias,
                                                       const float* __restrict__ A_log,
                                                       const float* __restrict__ Dp,
                                                       const short* __restrict__ lstate) {
    const int bhc = blockIdx.x;
    const int c = bhc & (NCHUNK - 1), bh = bhc >> 6, h = bh & (NHEADS - 1), b = bh >> 3;
    const int tid = threadIdx.x, lane = tid & 63, wid = tid >> 6;
    __shared__ short Bs[64 * LSTR];   // B rows [t][n]
    __shared__ short Cs[64 * LSTR];   // C rows [s][n]
    __shared__ short XT[64 * LSTR];   // X^T [p][t]
    __shared__ short SP[64 * LSTR];   // prefix state rows [p][n]
    __shared__ short Ms[64 * LSTR];   // masked scores rows [s][t]
    __shared__ float cums[CHUNK];
    __shared__ float dtss[CHUNK];
    const size_t row0 = (size_t)b * SEQ + (size_t)c * CHUNK;

#pragma unroll
    for (int r = 0; r < 4; ++r) {
        const int idx  = tid + r * 256;
        const int trow = idx >> 4;
        const int c4   = (idx & 15) * 4;
        const short* rp = xbc + (row0 + trow) * CONVDIM;
        const short4 xv = *(const short4*)(rp + h * 64 + c4);
        *(short4*)(Bs + trow * LSTR + c4) = *(const short4*)(rp + DINNER + c4);
        *(short4*)(Cs + trow * LSTR + c4) = *(const short4*)(rp + DINNER + DSTATE + c4);
        XT[(c4 + 0) * LSTR + trow] = xv.x;
        XT[(c4 + 1) * LSTR + trow] = xv.y;
        XT[(c4 + 2) * LSTR + trow] = xv.z;
        XT[(c4 + 3) * LSTR + trow] = xv.w;
    }
#pragma unroll
    for (int r = 0; r < 4; ++r) {
        const int idx = tid + r * 256;
        const int p = idx >> 4, n4 = (idx & 15) * 4;
        *(short4*)(SP + p * LSTR + n4) =
            *(const short4*)(lstate + ((size_t)bhc << 12) + p * 64 + n4);
    }
    const float aneg  = -__expf(A_log[h]);
    const float dbias = dt_bias[h];
    if (tid < 64) {
        const float draw = dt[(row0 + tid) * NHEADS + h] + dbias;
        const float dtv  = (draw > 20.f) ? draw : log1pf(__expf(draw));
        float cum = aneg * dtv;
#pragma unroll
        for (int off = 1; off < 64; off <<= 1) {
            const float nv = __shfl_up(cum, off);
            if (lane >= off) cum += nv;
        }
        cums[tid] = cum;
        dtss[tid] = dtv;
    }
    __syncthreads();

    // G = C @ B^T (over n)
    f32x4 accG[4];
#pragma unroll
    for (int tf = 0; tf < 4; ++tf) accG[tf] = (f32x4)0.f;
#pragma unroll
    for (int ks = 0; ks < 2; ++ks) {
        const bf16x8 af = *(const bf16x8*)(Cs + (wid * 16 + (lane & 15)) * LSTR + ks * 32 + (lane >> 4) * 8);
#pragma unroll
        for (int tf = 0; tf < 4; ++tf) {
            const bf16x8 bfv = *(const bf16x8*)(Bs + (tf * 16 + (lane & 15)) * LSTR + ks * 32 + (lane >> 4) * 8);
            accG[tf] = __builtin_amdgcn_mfma_f32_16x16x32_bf16(af, bfv, accG[tf], 0, 0, 0);
        }
    }
    // causal mask + decay scale -> Ms (bf16)
    const int srow0 = wid * 16 + (lane >> 4) * 4;
#pragma unroll
    for (int tf = 0; tf < 4; ++tf) {
        const int t = tf * 16 + (lane & 15);
        const float ct  = cums[t];
        const float dtt = dtss[t];
#pragma unroll
        for (int reg = 0; reg < 4; ++reg) {
            const int s = srow0 + reg;
            const float m = (t <= s) ? accG[tf][reg] * __expf(cums[s] - ct) * dtt : 0.f;
            Ms[s * LSTR + t] = f2bf(m);
        }
    }
    __syncthreads();

    // Y1 = M @ X ; Y2 = C @ SP^T
    f32x4 acc1[4], acc2[4];
#pragma unroll
    for (int pf = 0; pf < 4; ++pf) { acc1[pf] = (f32x4)0.f; acc2[pf] = (f32x4)0.f; }
#pragma unroll
    for (int ks = 0; ks < 2; ++ks) {
        const bf16x8 am = *(const bf16x8*)(Ms + (wid * 16 + (lane & 15)) * LSTR + ks * 32 + (lane >> 4) * 8);
        const bf16x8 ac = *(const bf16x8*)(Cs + (wid * 16 + (lane & 15)) * LSTR + ks * 32 + (lane >> 4) * 8);
#pragma unroll
        for (int pf = 0; pf < 4; ++pf) {
            const bf16x8 bx = *(const bf16x8*)(XT + (pf * 16 + (lane & 15)) * LSTR + ks * 32 + (lane >> 4) * 8);
            const bf16x8 bs = *(const bf16x8*)(SP + (pf * 16 + (lane & 15)) * LSTR + ks * 32 + (lane >> 4) * 8);
            acc1[pf] = __builtin_amdgcn_mfma_f32_16x16x32_bf16(am, bx, acc1[pf], 0, 0, 0);
            acc2[pf] = __builtin_amdgcn_mfma_f32_16x16x32_bf16(ac, bs, acc2[pf], 0, 0, 0);
        }
    }
    const float dpv = Dp[h];
    float es[4];
#pragma unroll
    for (int reg = 0; reg < 4; ++reg) es[reg] = __expf(cums[srow0 + reg]);
#pragma unroll
    for (int pf = 0; pf < 4; ++pf) {
        const int p = pf * 16 + (lane & 15);
#pragma unroll
        for (int reg = 0; reg < 4; ++reg) {
            const int s = srow0 + reg;
            const float xv = bf2f(XT[p * LSTR + s]);
            xbc[(row0 + s) * CONVDIM + h * 64 + p] =
                f2bf(acc1[pf][reg] + es[reg] * acc2[pf][reg] + dpv * xv);
        }
    }
}

// ---------------- y(bf16)*silu(z) -> rmsnorm (D=512) -> bf16 yzn ----------------
__global__ __launch_bounds__(256) void gate_norm_kernel(const short* __restrict__ xbc,
                                                        const short* __restrict__ zxb,
                                                        const float* __restrict__ gw,
                                                        short* __restrict__ yzn) {
    const int row  = blockIdx.x * 4 + (threadIdx.x >> 6);
    const int lane = threadIdx.x & 63;
    const bf16x8 yv8 = *(const bf16x8*)(xbc + (size_t)row * CONVDIM + lane * 8);
    const bf16x8 zv  = *(const bf16x8*)(zxb + (size_t)row * DPROJ + lane * 8);
    float v[8];
#pragma unroll
    for (int i = 0; i < 8; ++i) {
        const float z = bf2f(zv[i]);
        v[i] = bf2f(yv8[i]) * z / (1.f + __expf(-z));
    }
    float ss = 0.f;
#pragma unroll
    for (int i = 0; i < 8; ++i) ss += v[i] * v[i];
#pragma unroll
    for (int off = 1; off < 64; off <<= 1) ss += __shfl_xor(ss, off);
    const float rs = rsqrtf(ss * (1.0f / DINNER) + 1e-5f);
    const float* g = gw + lane * 8;
    short8v o;
#pragma unroll
    for (int i = 0; i < 8; ++i) o[i] = f2bf(v[i] * rs * g[i]);
    *(short8v*)(yzn + (size_t)row * DINNER + lane * 8) = o;
}

// ---------------- launch ----------------
extern "C" void kernel_launch(void* const* d_in, const int* in_sizes, int n_in,
                              void* d_out, int out_size, void* d_ws, size_t ws_size,
                              hipStream_t stream) {
    (void)in_sizes; (void)n_in; (void)out_size; (void)d_ws; (void)ws_size;
    const float* x      = (const float*)d_in[0];
    const float* W_in   = (const float*)d_in[1];
    const float* conv_w = (const float*)d_in[2];
    const float* conv_b = (const float*)d_in[3];
    const float* dt_b   = (const float*)d_in[4];
    const float* A_log  = (const float*)d_in[5];
    const float* Dp     = (const float*)d_in[6];
    const float* g_w    = (const float*)d_in[7];
    const float* n_w    = (const float*)d_in[8];
    const float* W_out  = (const float*)d_in[9];
    float* out = (float*)d_out;

    short *xn, *zxb, *xbc, *yzn, *winb, *woutb, *lst;
    float *dtv, *dcy;
    hipGetSymbolAddress((void**)&xn,    HIP_SYMBOL(g_xn));
    hipGetSymbolAddress((void**)&zxb,   HIP_SYMBOL(g_zxb));
    hipGetSymbolAddress((void**)&xbc,   HIP_SYMBOL(g_xbc));
    hipGetSymbolAddress((void**)&dtv,   HIP_SYMBOL(g_dt));
    hipGetSymbolAddress((void**)&yzn,   HIP_SYMBOL(g_yzn));
    hipGetSymbolAddress((void**)&lst,   HIP_SYMBOL(g_lstate));
    hipGetSymbolAddress((void**)&dcy,   HIP_SYMBOL(g_decayC));
    hipGetSymbolAddress((void**)&winb,  HIP_SYMBOL(g_Winb));
    hipGetSymbolAddress((void**)&woutb, HIP_SYMBOL(g_Woutb));

    convert_bf16_kernel<<<(NPAD * DMODEL) / 256, 256, 0, stream>>>(
        W_in, winb, DPROJ * DMODEL, NPAD * DMODEL);
    convert_bf16_kernel<<<(DMODEL * DINNER) / 256, 256, 0, stream>>>(
        W_out, woutb, DMODEL * DINNER, DMODEL * DINNER);

    rmsnorm_dt_kernel<<<NROWS / 4, 256, 0, stream>>>(x, n_w, W_in, xn, dtv);

    gemm_bf16_nt<false, short><<<(NPAD / 128) * (NROWS / 128), 256, 0, stream>>>(
        xn, winb, nullptr, zxb, NPAD / 128, NROWS, DPROJ, DMODEL);

    conv_silu_kernel<<<(NROWS / 4 * 80) / 256, 256, 0, stream>>>(zxb, conv_w, conv_b, xbc);

    chunk_state_mfma<<<BATCH * NHEADS * NCHUNK, 256, 0, stream>>>(dtv, xbc, dt_b, A_log, lst, dcy);
    state_prefix_kernel<<<(BATCH * NHEADS * HEADDIM * DSTATE) / 256, 256, 0, stream>>>(lst, dcy);
    chunk_scan_mfma<<<BATCH * NHEADS * NCHUNK, 256, 0, stream>>>(dtv, xbc, dt_b, A_log, Dp, lst);

    gate_norm_kernel<<<NROWS / 4, 256, 0, stream>>>(xbc, zxb, g_w, yzn);

    gemm_bf16_nt<true, float><<<(DMODEL / 128) * (NROWS / 128), 256, 0, stream>>>(
        yzn, woutb, x, out, DMODEL / 128, NROWS, DMODEL, DINNER);
}

// Round 9
// 211.843 us; speedup vs baseline: 1.1106x; 1.1106x over previous
//
#include <hip/hip_runtime.h>
#include <math.h>

#define BATCH   8
#define SEQ     4096
#define DMODEL  256
#define DINNER  512
#define DSTATE  64
#define NHEADS  8
#define HEADDIM 64
#define CONVDIM 640          // DINNER + 2*DSTATE
#define DPROJ   1160         // 2*DINNER + 2*DSTATE + NHEADS
#define NROWS   (BATCH*SEQ)  // 32768
#define CHUNK   64
#define NCHUNK  (SEQ/CHUNK)  // 64
#define NPAD    1280         // DPROJ padded to mult of 128 for bf16 W_in
#define LSTR    72           // LDS row stride (shorts)

typedef short bf16x8 __attribute__((ext_vector_type(8)));
typedef short short8v __attribute__((ext_vector_type(8)));
typedef float f32x4 __attribute__((ext_vector_type(4)));

// ---- static workspace (BSS) ----
__device__ short g_xn[(size_t)NROWS * DMODEL];      // bf16 16.8 MB
__device__ short g_zxb[(size_t)NROWS * DPROJ];      // bf16 76.0 MB (z | xBC | unused dt)
__device__ short g_xbc[(size_t)NROWS * CONVDIM];    // bf16 42.0 MB (conv out; x-slice later overwritten by y)
__device__ float g_dt[(size_t)NROWS * NHEADS];      // fp32  1.0 MB (raw dt, pre-bias)
__device__ short g_yzn[(size_t)NROWS * DINNER];     // bf16 33.5 MB
__device__ short g_lstate[(size_t)BATCH * NHEADS * NCHUNK * HEADDIM * DSTATE]; // bf16 33.5 MB
__device__ float g_decayC[BATCH * NHEADS * NCHUNK];
__device__ short g_Winb[(size_t)NPAD * DMODEL];     // bf16 W_in, zero-padded rows
__device__ short g_Woutb[(size_t)DMODEL * DINNER];  // bf16 W_out

__device__ __forceinline__ short f2bf(float f) {
    unsigned u = __float_as_uint(f);
    u += 0x7fff + ((u >> 16) & 1);
    return (short)(u >> 16);
}
__device__ __forceinline__ float bf2f(short s) {
    return __uint_as_float(((unsigned)(unsigned short)s) << 16);
}

__device__ __forceinline__ void stage16(const void* gsrc, void* ldst) {
    __builtin_amdgcn_global_load_lds(
        (const __attribute__((address_space(1))) void*)gsrc,
        (__attribute__((address_space(3))) void*)ldst, 16, 0, 0);
}

// ---------------- weight convert: fp32 -> bf16 with flat zero-pad tail ----------------
__global__ __launch_bounds__(256) void convert_bf16_kernel(const float* __restrict__ src,
                                                           short* __restrict__ dst,
                                                           int n_valid, int n_total) {
    const int i = blockIdx.x * 256 + threadIdx.x;
    if (i < n_total) dst[i] = (i < n_valid) ? f2bf(src[i]) : (short)0;
}

// ---------------- rmsnorm of x (D=256) -> bf16 xn AND exact fp32 dt (8 heads) ----------
__global__ __launch_bounds__(256) void rmsnorm_dt_kernel(const float* __restrict__ x,
                                                         const float* __restrict__ w,
                                                         const float* __restrict__ W_in,
                                                         short* __restrict__ xn,
                                                         float* __restrict__ dt) {
    const int row  = blockIdx.x * 4 + (threadIdx.x >> 6);
    const int lane = threadIdx.x & 63;
    const float4 v = *(const float4*)(x + (size_t)row * DMODEL + lane * 4);
    float ss = v.x * v.x + v.y * v.y + v.z * v.z + v.w * v.w;
#pragma unroll
    for (int off = 1; off < 64; off <<= 1) ss += __shfl_xor(ss, off);
    const float rs = rsqrtf(ss * (1.0f / DMODEL) + 1.1920929e-7f);
    const float4 wv = *(const float4*)(w + lane * 4);
    const float4 xn4 = make_float4(v.x * rs * wv.x, v.y * rs * wv.y,
                                   v.z * rs * wv.z, v.w * rs * wv.w);
    short4 o;
    o.x = f2bf(xn4.x); o.y = f2bf(xn4.y); o.z = f2bf(xn4.z); o.w = f2bf(xn4.w);
    *(short4*)(xn + (size_t)row * DMODEL + lane * 4) = o;
#pragma unroll
    for (int h = 0; h < NHEADS; ++h) {
        const float4 ww = *(const float4*)(W_in + (size_t)(DPROJ - NHEADS + h) * DMODEL + lane * 4);
        float p = xn4.x * ww.x + xn4.y * ww.y + xn4.z * ww.z + xn4.w * ww.w;
#pragma unroll
        for (int off = 1; off < 64; off <<= 1) p += __shfl_xor(p, off);
        if (lane == 0) dt[(size_t)row * NHEADS + h] = p;
    }
}

// ---------------- bf16 MFMA GEMM: C[M][N] = A[M][K] * B[N][K]^T ----------
// XCD-chunked 1-D grid swizzle. B rows are staged PERMUTED within each 64-row
// group (slot n*16+j holds B row 4j+n) so each lane's 4 n-frag accumulators
// are 4 consecutive output columns -> packed 8B/16B stores (64 -> 16 stores).
template <bool RES, typename OUT>
__global__ __launch_bounds__(256) void gemm_bf16_nt(const short* __restrict__ A,
                                                    const short* __restrict__ B,
                                                    const float* __restrict__ R,
                                                    OUT* __restrict__ C,
                                                    int NX, int M, int N, int K) {
    const int L   = blockIdx.x;
    const int xcd = L & 7;
    const int r   = L >> 3;
    const int mstrips_per_xcd = (M / 128) >> 3;
    const int mblk = xcd * mstrips_per_xcd + r / NX;
    const int nblk = r % NX;
    const int m0 = mblk * 128, n0 = nblk * 128;

    __shared__ __align__(16) short Asl[128 * 32];
    __shared__ __align__(16) short Bsl[128 * 32];
    const int tid  = threadIdx.x;
    const int lane = tid & 63;
    const int wid  = tid >> 6;
    const int wrow = (wid >> 1) * 64, wcol = (wid & 1) * 64;

    f32x4 acc[4][4];
#pragma unroll
    for (int m = 0; m < 4; ++m)
#pragma unroll
        for (int n = 0; n < 4; ++n) acc[m][n] = (f32x4)0.f;

    const int wbase = (tid & 0xC0) * 8;

    for (int k0 = 0; k0 < K; k0 += 32) {
#pragma unroll
        for (int rr = 0; rr < 2; ++rr) {
            const int idx = rr * 256 + tid;
            const int row = idx >> 2;              // LDS slot row 0..127
            const int ko  = (idx & 3) * 8;
            // permuted source row: within each 64-row group, slot s' holds row
            // ((s'&15)<<2) | (s'>>4)  (inverse of read mapping)
            const int r6 = row & 63;
            const int brow = (row & 64) + (((r6 & 15) << 2) | (r6 >> 4));
            stage16(A + (size_t)(m0 + row) * K + k0 + ko, Asl + rr * 2048 + wbase);
            stage16(B + (size_t)(n0 + brow) * K + k0 + ko, Bsl + rr * 2048 + wbase);
        }
        __syncthreads();
        bf16x8 af[4], bfr[4];
#pragma unroll
        for (int m = 0; m < 4; ++m)
            af[m] = *(const bf16x8*)(Asl + (wrow + m * 16 + (lane & 15)) * 32 + (lane >> 4) * 8);
#pragma unroll
        for (int n = 0; n < 4; ++n)
            bfr[n] = *(const bf16x8*)(Bsl + (wcol + n * 16 + (lane & 15)) * 32 + (lane >> 4) * 8);
#pragma unroll
        for (int m = 0; m < 4; ++m)
#pragma unroll
            for (int n = 0; n < 4; ++n)
                acc[m][n] = __builtin_amdgcn_mfma_f32_16x16x32_bf16(af[m], bfr[n], acc[m][n], 0, 0, 0);
        __syncthreads();
    }

    // acc[m][n] lane (hi=lane>>4, j=lane&15) holds C[m0+wrow+m*16+hi*4+reg][n0+wcol+4j+n]
    const int r0 = (lane >> 4) * 4;
    const int gcol = n0 + wcol + (lane & 15) * 4;
#pragma unroll
    for (int m = 0; m < 4; ++m) {
        const int grow = m0 + wrow + m * 16 + r0;
        if (gcol < N) {
#pragma unroll
            for (int reg = 0; reg < 4; ++reg) {
                if constexpr (sizeof(OUT) == 2) {
                    short4 o;
                    o.x = f2bf(acc[m][0][reg]); o.y = f2bf(acc[m][1][reg]);
                    o.z = f2bf(acc[m][2][reg]); o.w = f2bf(acc[m][3][reg]);
                    *(short4*)(C + (size_t)(grow + reg) * N + gcol) = o;
                } else {
                    f32x4 v;
                    v[0] = acc[m][0][reg]; v[1] = acc[m][1][reg];
                    v[2] = acc[m][2][reg]; v[3] = acc[m][3][reg];
                    if (RES) v += *(const f32x4*)(R + (size_t)(grow + reg) * N + gcol);
                    *(f32x4*)(C + (size_t)(grow + reg) * N + gcol) = v;
                }
            }
        }
    }
}

// ---- depthwise causal conv(4) + bias + SiLU: sliding window, 4 rows x 8 ch per thread ----
__global__ __launch_bounds__(256) void conv_silu_kernel(const short* __restrict__ zxb,
                                                        const float* __restrict__ cw,
                                                        const float* __restrict__ cb,
                                                        short* __restrict__ xbc) {
    const int idx = blockIdx.x * 256 + threadIdx.x;   // over (NROWS/4)*80
    const int c8  = (idx % 80) * 8;
    const int bl0 = (idx / 80) * 4;                   // first of 4 rows
    const int l0  = bl0 & (SEQ - 1);
    const short* src = zxb + (size_t)bl0 * DPROJ + DINNER + c8;

    float4 w4[8];
    float bias[8];
#pragma unroll
    for (int j = 0; j < 8; ++j) w4[j] = *(const float4*)(cw + (c8 + j) * 4);
    {
        const float4 b0 = *(const float4*)(cb + c8);
        const float4 b1 = *(const float4*)(cb + c8 + 4);
        bias[0] = b0.x; bias[1] = b0.y; bias[2] = b0.z; bias[3] = b0.w;
        bias[4] = b1.x; bias[5] = b1.y; bias[6] = b1.z; bias[7] = b1.w;
    }

    bf16x8 rowv[7];                                   // rows l0-3 .. l0+3
#pragma unroll
    for (int m = 0; m < 7; ++m) {
        if (l0 + m - 3 >= 0)
            rowv[m] = *(const bf16x8*)(src + (ptrdiff_t)(m - 3) * DPROJ);
        else
            rowv[m] = (bf16x8)0;
    }

#pragma unroll
    for (int r = 0; r < 4; ++r) {
        float acc[8];
#pragma unroll
        for (int j = 0; j < 8; ++j) acc[j] = bias[j];
#pragma unroll
        for (int k = 0; k < 4; ++k) {
            const bf16x8 tap = rowv[r + k];
#pragma unroll
            for (int j = 0; j < 8; ++j)
                acc[j] = fmaf(bf2f(tap[j]), ((const float*)&w4[j])[k], acc[j]);
        }
        short8v o;
#pragma unroll
        for (int j = 0; j < 8; ++j) {
            const float s = acc[j];
            o[j] = f2bf(s / (1.f + __expf(-s)));
        }
        *(short8v*)(xbc + (size_t)(bl0 + r) * CONVDIM + c8) = o;
    }
}

// ---------------- scan pass 1 (MFMA): L[p][n] = sum_t X[t][p] * (w_t * B[t][n]) ----------
// BT slot rows permuted (slot n*16+j holds state-col 4j+n) -> packed short4 stores.
__global__ __launch_bounds__(256) void chunk_state_mfma(const float* __restrict__ dt,
                                                        const short* __restrict__ xbc,
                                                        const float* __restrict__ dt_bias,
                                                        const float* __restrict__ A_log,
                                                        short* __restrict__ lstate,
                                                        float* __restrict__ decayC) {
    const int bhc = blockIdx.x;
    const int c = bhc & (NCHUNK - 1), bh = bhc >> 6, h = bh & (NHEADS - 1), b = bh >> 3;
    const int tid = threadIdx.x, lane = tid & 63, wid = tid >> 6;
    __shared__ short XT[64 * LSTR];   // XT[p][t]
    __shared__ short BT[64 * LSTR];   // (w*B)^T, slot-permuted
    __shared__ float wsh[CHUNK];
    const size_t row0 = (size_t)b * SEQ + (size_t)c * CHUNK;

    const float aneg  = -__expf(A_log[h]);
    const float dbias = dt_bias[h];
    if (tid < 64) {
        const float draw = dt[(row0 + tid) * NHEADS + h] + dbias;
        const float dtv  = (draw > 20.f) ? draw : log1pf(__expf(draw));
        float cum = aneg * dtv;
#pragma unroll
        for (int off = 1; off < 64; off <<= 1) {
            const float nv = __shfl_up(cum, off);
            if (lane >= off) cum += nv;
        }
        const float total = __shfl(cum, 63);
        wsh[tid] = __expf(total - cum) * dtv;
        if (tid == 63) decayC[bhc] = __expf(cum);
    }
    __syncthreads();

#pragma unroll
    for (int r = 0; r < 4; ++r) {
        const int idx  = tid + r * 256;
        const int trow = idx >> 4;
        const int q    = idx & 15;                 // channel group: channels 4q..4q+3
        const int c4   = q * 4;
        const short* rp = xbc + (row0 + trow) * CONVDIM;
        const short4 xv = *(const short4*)(rp + h * 64 + c4);
        const short4 bv = *(const short4*)(rp + DINNER + c4);
        const float w = wsh[trow];
        XT[(c4 + 0) * LSTR + trow] = xv.x;
        XT[(c4 + 1) * LSTR + trow] = xv.y;
        XT[(c4 + 2) * LSTR + trow] = xv.z;
        XT[(c4 + 3) * LSTR + trow] = xv.w;
        // channel c4+i -> slot (i*16 + q)
        BT[(0 * 16 + q) * LSTR + trow] = f2bf(bf2f(bv.x) * w);
        BT[(1 * 16 + q) * LSTR + trow] = f2bf(bf2f(bv.y) * w);
        BT[(2 * 16 + q) * LSTR + trow] = f2bf(bf2f(bv.z) * w);
        BT[(3 * 16 + q) * LSTR + trow] = f2bf(bf2f(bv.w) * w);
    }
    __syncthreads();

    f32x4 acc[4];
#pragma unroll
    for (int n = 0; n < 4; ++n) acc[n] = (f32x4)0.f;
#pragma unroll
    for (int ks = 0; ks < 2; ++ks) {
        const bf16x8 af = *(const bf16x8*)(XT + (wid * 16 + (lane & 15)) * LSTR + ks * 32 + (lane >> 4) * 8);
#pragma unroll
        for (int n = 0; n < 4; ++n) {
            const bf16x8 bfv = *(const bf16x8*)(BT + (n * 16 + (lane & 15)) * LSTR + ks * 32 + (lane >> 4) * 8);
            acc[n] = __builtin_amdgcn_mfma_f32_16x16x32_bf16(af, bfv, acc[n], 0, 0, 0);
        }
    }
    // acc[n] lane (hi,j) = L[wid*16+hi*4+reg][4j+n] -> packed short4
    short* lp = lstate + ((size_t)bhc << 12);
    const int ncol = (lane & 15) * 4;
#pragma unroll
    for (int reg = 0; reg < 4; ++reg) {
        const int p = wid * 16 + (lane >> 4) * 4 + reg;
        short4 o;
        o.x = f2bf(acc[0][reg]); o.y = f2bf(acc[1][reg]);
        o.z = f2bf(acc[2][reg]); o.w = f2bf(acc[3][reg]);
        *(short4*)(lp + p * 64 + ncol) = o;
    }
}

// ---------------- scan pass 2: inter-chunk recurrence (bf16 lstate, fp32 carry) --------
__global__ __launch_bounds__(256) void state_prefix_kernel(short* __restrict__ lstate,
                                                           const float* __restrict__ decayC) {
    const int idx = blockIdx.x * 256 + threadIdx.x;   // over BATCH*NHEADS*4096
    const int bh = idx >> 12;
    const int pn = idx & 4095;
    float S = 0.f;
    for (int c = 0; c < NCHUNK; ++c) {
        short* ptr = lstate + (((size_t)bh * NCHUNK + c) << 12) + pn;
        const float l = bf2f(*ptr);
        *ptr = f2bf(S);
        S = fmaf(S, decayC[bh * NCHUNK + c], l);
    }
}

// ---- scan pass 3 (MFMA): Y = mask(C@B^T)@X + exp(cum)*(C@SP^T) + Dp*X; y (bf16) in place --
// XT/SP slot rows permuted (slot pf*16+j holds p-row 4j+pf) -> packed short4 y stores.
__global__ __launch_bounds__(256) void chunk_scan_mfma(const float* __restrict__ dt,
                                                       short* __restrict__ xbc,
                                                       const float* __restrict__ dt_bias,
                                                       const float* __restrict__ A_log,
                                                       const float* __restrict__ Dp,
                                                       const short* __restrict__ lstate) {
    const int bhc = blockIdx.x;
    const int c = bhc & (NCHUNK - 1), bh = bhc >> 6, h = bh & (NHEADS - 1), b = bh >> 3;
    const int tid = threadIdx.x, lane = tid & 63, wid = tid >> 6;
    __shared__ short Bs[64 * LSTR];   // B rows [t][n]
    __shared__ short Cs[64 * LSTR];   // C rows [s][n]
    __shared__ short XT[64 * LSTR];   // X^T, slot-permuted
    __shared__ short SP[64 * LSTR];   // prefix state, slot-permuted
    __shared__ short Ms[64 * LSTR];   // masked scores rows [s][t]
    __shared__ float cums[CHUNK];
    __shared__ float dtss[CHUNK];
    const size_t row0 = (size_t)b * SEQ + (size_t)c * CHUNK;

#pragma unroll
    for (int r = 0; r < 4; ++r) {
        const int idx  = tid + r * 256;
        const int trow = idx >> 4;
        const int q    = idx & 15;
        const int c4   = q * 4;
        const short* rp = xbc + (row0 + trow) * CONVDIM;
        const short4 xv = *(const short4*)(rp + h * 64 + c4);
        *(short4*)(Bs + trow * LSTR + c4) = *(const short4*)(rp + DINNER + c4);
        *(short4*)(Cs + trow * LSTR + c4) = *(const short4*)(rp + DINNER + DSTATE + c4);
        // p-row c4+i -> slot (i*16 + q)
        XT[(0 * 16 + q) * LSTR + trow] = xv.x;
        XT[(1 * 16 + q) * LSTR + trow] = xv.y;
        XT[(2 * 16 + q) * LSTR + trow] = xv.z;
        XT[(3 * 16 + q) * LSTR + trow] = xv.w;
    }
#pragma unroll
    for (int r = 0; r < 4; ++r) {
        const int idx = tid + r * 256;
        const int p = idx >> 4, n4 = (idx & 15) * 4;
        const int pslot = ((p & 3) << 4) | (p >> 2);
        *(short4*)(SP + pslot * LSTR + n4) =
            *(const short4*)(lstate + ((size_t)bhc << 12) + p * 64 + n4);
    }
    const float aneg  = -__expf(A_log[h]);
    const float dbias = dt_bias[h];
    if (tid < 64) {
        const float draw = dt[(row0 + tid) * NHEADS + h] + dbias;
        const float dtv  = (draw > 20.f) ? draw : log1pf(__expf(draw));
        float cum = aneg * dtv;
#pragma unroll
        for (int off = 1; off < 64; off <<= 1) {
            const float nv = __shfl_up(cum, off);
            if (lane >= off) cum += nv;
        }
        cums[tid] = cum;
        dtss[tid] = dtv;
    }
    __syncthreads();

    // G = C @ B^T (over n)
    f32x4 accG[4];
#pragma unroll
    for (int tf = 0; tf < 4; ++tf) accG[tf] = (f32x4)0.f;
#pragma unroll
    for (int ks = 0; ks < 2; ++ks) {
        const bf16x8 af = *(const bf16x8*)(Cs + (wid * 16 + (lane & 15)) * LSTR + ks * 32 + (lane >> 4) * 8);
#pragma unroll
        for (int tf = 0; tf < 4; ++tf) {
            const bf16x8 bfv = *(const bf16x8*)(Bs + (tf * 16 + (lane & 15)) * LSTR + ks * 32 + (lane >> 4) * 8);
            accG[tf] = __builtin_amdgcn_mfma_f32_16x16x32_bf16(af, bfv, accG[tf], 0, 0, 0);
        }
    }
    // causal mask + decay scale -> Ms (bf16)
    const int srow0 = wid * 16 + (lane >> 4) * 4;
#pragma unroll
    for (int tf = 0; tf < 4; ++tf) {
        const int t = tf * 16 + (lane & 15);
        const float ct  = cums[t];
        const float dtt = dtss[t];
#pragma unroll
        for (int reg = 0; reg < 4; ++reg) {
            const int s = srow0 + reg;
            const float m = (t <= s) ? accG[tf][reg] * __expf(cums[s] - ct) * dtt : 0.f;
            Ms[s * LSTR + t] = f2bf(m);
        }
    }
    __syncthreads();

    // Y1 = M @ X ; Y2 = C @ SP^T  (B-operands slot-permuted: pos j of frag pf = p-row 4j+pf)
    f32x4 acc1[4], acc2[4];
#pragma unroll
    for (int pf = 0; pf < 4; ++pf) { acc1[pf] = (f32x4)0.f; acc2[pf] = (f32x4)0.f; }
#pragma unroll
    for (int ks = 0; ks < 2; ++ks) {
        const bf16x8 am = *(const bf16x8*)(Ms + (wid * 16 + (lane & 15)) * LSTR + ks * 32 + (lane >> 4) * 8);
        const bf16x8 ac = *(const bf16x8*)(Cs + (wid * 16 + (lane & 15)) * LSTR + ks * 32 + (lane >> 4) * 8);
#pragma unroll
        for (int pf = 0; pf < 4; ++pf) {
            const bf16x8 bx = *(const bf16x8*)(XT + (pf * 16 + (lane & 15)) * LSTR + ks * 32 + (lane >> 4) * 8);
            const bf16x8 bs = *(const bf16x8*)(SP + (pf * 16 + (lane & 15)) * LSTR + ks * 32 + (lane >> 4) * 8);
            acc1[pf] = __builtin_amdgcn_mfma_f32_16x16x32_bf16(am, bx, acc1[pf], 0, 0, 0);
            acc2[pf] = __builtin_amdgcn_mfma_f32_16x16x32_bf16(ac, bs, acc2[pf], 0, 0, 0);
        }
    }
    const float dpv = Dp[h];
    float es[4];
#pragma unroll
    for (int reg = 0; reg < 4; ++reg) es[reg] = __expf(cums[srow0 + reg]);
    // acc1/acc2[pf] lane (hi,j): Y[srow0+reg][p = 4j+pf]; XT slot of p=4j+pf is pf*16+j
    const int j = lane & 15;
#pragma unroll
    for (int reg = 0; reg < 4; ++reg) {
        const int s = srow0 + reg;
        short4 o;
#pragma unroll
        for (int pf = 0; pf < 4; ++pf) {
            const float xv = bf2f(XT[(pf * 16 + j) * LSTR + s]);
            const float yv = acc1[pf][reg] + es[reg] * acc2[pf][reg] + dpv * xv;
            ((short*)&o)[pf] = f2bf(yv);
        }
        *(short4*)(xbc + (row0 + s) * CONVDIM + h * 64 + j * 4) = o;
    }
}

// ---------------- y(bf16)*silu(z) -> rmsnorm (D=512) -> bf16 yzn ----------------
__global__ __launch_bounds__(256) void gate_norm_kernel(const short* __restrict__ xbc,
                                                        const short* __restrict__ zxb,
                                                        const float* __restrict__ gw,
                                                        short* __restrict__ yzn) {
    const int row  = blockIdx.x * 4 + (threadIdx.x >> 6);
    const int lane = threadIdx.x & 63;
    const bf16x8 yv8 = *(const bf16x8*)(xbc + (size_t)row * CONVDIM + lane * 8);
    const bf16x8 zv  = *(const bf16x8*)(zxb + (size_t)row * DPROJ + lane * 8);
    float v[8];
#pragma unroll
    for (int i = 0; i < 8; ++i) {
        const float z = bf2f(zv[i]);
        v[i] = bf2f(yv8[i]) * z / (1.f + __expf(-z));
    }
    float ss = 0.f;
#pragma unroll
    for (int i = 0; i < 8; ++i) ss += v[i] * v[i];
#pragma unroll
    for (int off = 1; off < 64; off <<= 1) ss += __shfl_xor(ss, off);
    const float rs = rsqrtf(ss * (1.0f / DINNER) + 1e-5f);
    const float* g = gw + lane * 8;
    short8v o;
#pragma unroll
    for (int i = 0; i < 8; ++i) o[i] = f2bf(v[i] * rs * g[i]);
    *(short8v*)(yzn + (size_t)row * DINNER + lane * 8) = o;
}

// ---------------- launch ----------------
extern "C" void kernel_launch(void* const* d_in, const int* in_sizes, int n_in,
                              void* d_out, int out_size, void* d_ws, size_t ws_size,
                              hipStream_t stream) {
    (void)in_sizes; (void)n_in; (void)out_size; (void)d_ws; (void)ws_size;
    const float* x      = (const float*)d_in[0];
    const float* W_in   = (const float*)d_in[1];
    const float* conv_w = (const float*)d_in[2];
    const float* conv_b = (const float*)d_in[3];
    const float* dt_b   = (const float*)d_in[4];
    const float* A_log  = (const float*)d_in[5];
    const float* Dp     = (const float*)d_in[6];
    const float* g_w    = (const float*)d_in[7];
    const float* n_w    = (const float*)d_in[8];
    const float* W_out  = (const float*)d_in[9];
    float* out = (float*)d_out;

    short *xn, *zxb, *xbc, *yzn, *winb, *woutb, *lst;
    float *dtv, *dcy;
    hipGetSymbolAddress((void**)&xn,    HIP_SYMBOL(g_xn));
    hipGetSymbolAddress((void**)&zxb,   HIP_SYMBOL(g_zxb));
    hipGetSymbolAddress((void**)&xbc,   HIP_SYMBOL(g_xbc));
    hipGetSymbolAddress((void**)&dtv,   HIP_SYMBOL(g_dt));
    hipGetSymbolAddress((void**)&yzn,   HIP_SYMBOL(g_yzn));
    hipGetSymbolAddress((void**)&lst,   HIP_SYMBOL(g_lstate));
    hipGetSymbolAddress((void**)&dcy,   HIP_SYMBOL(g_decayC));
    hipGetSymbolAddress((void**)&winb,  HIP_SYMBOL(g_Winb));
    hipGetSymbolAddress((void**)&woutb, HIP_SYMBOL(g_Woutb));

    convert_bf16_kernel<<<(NPAD * DMODEL) / 256, 256, 0, stream>>>(
        W_in, winb, DPROJ * DMODEL, NPAD * DMODEL);
    convert_bf16_kernel<<<(DMODEL * DINNER) / 256, 256, 0, stream>>>(
        W_out, woutb, DMODEL * DINNER, DMODEL * DINNER);

    rmsnorm_dt_kernel<<<NROWS / 4, 256, 0, stream>>>(x, n_w, W_in, xn, dtv);

    gemm_bf16_nt<false, short><<<(NPAD / 128) * (NROWS / 128), 256, 0, stream>>>(
        xn, winb, nullptr, zxb, NPAD / 128, NROWS, DPROJ, DMODEL);

    conv_silu_kernel<<<(NROWS / 4 * 80) / 256, 256, 0, stream>>>(zxb, conv_w, conv_b, xbc);

    chunk_state_mfma<<<BATCH * NHEADS * NCHUNK, 256, 0, stream>>>(dtv, xbc, dt_b, A_log, lst, dcy);
    state_prefix_kernel<<<(BATCH * NHEADS * HEADDIM * DSTATE) / 256, 256, 0, stream>>>(lst, dcy);
    chunk_scan_mfma<<<BATCH * NHEADS * NCHUNK, 256, 0, stream>>>(dtv, xbc, dt_b, A_log, Dp, lst);

    gate_norm_kernel<<<NROWS / 4, 256, 0, stream>>>(xbc, zxb, g_w, yzn);

    gemm_bf16_nt<true, float><<<(DMODEL / 128) * (NROWS / 128), 256, 0, stream>>>(
        yzn, woutb, x, out, DMODEL / 128, NROWS, DMODEL, DINNER);
}

// Round 10
// 193.762 us; speedup vs baseline: 1.2142x; 1.0933x over previous
//
#include <hip/hip_runtime.h>
#include <math.h>

#define BATCH   8
#define SEQ     4096
#define DMODEL  256
#define DINNER  512
#define DSTATE  64
#define NHEADS  8
#define HEADDIM 64
#define CONVDIM 640          // DINNER + 2*DSTATE
#define DPROJ   1160         // 2*DINNER + 2*DSTATE + NHEADS
#define NROWS   (BATCH*SEQ)  // 32768
#define CHUNK   64
#define NCHUNK  (SEQ/CHUNK)  // 64
#define NPAD    1280         // DPROJ padded to mult of 128 for bf16 W_in
#define LSTR    72           // LDS row stride (shorts)

typedef short bf16x8 __attribute__((ext_vector_type(8)));
typedef short short8v __attribute__((ext_vector_type(8)));
typedef float f32x4 __attribute__((ext_vector_type(4)));

// ---- static workspace (BSS) ----
__device__ short g_xn[(size_t)NROWS * DMODEL];      // bf16 16.8 MB
__device__ short g_zxb[(size_t)NROWS * DPROJ];      // bf16 76.0 MB (z | xBC | unused dt)
__device__ short g_xbc[(size_t)NROWS * CONVDIM];    // bf16 42.0 MB (conv out; x-slice later overwritten by y)
__device__ float g_dt[(size_t)NROWS * NHEADS];      // fp32  1.0 MB (raw dt, pre-bias)
__device__ short g_yzn[(size_t)NROWS * DINNER];     // bf16 33.5 MB
__device__ short g_lstate[(size_t)BATCH * NHEADS * NCHUNK * HEADDIM * DSTATE]; // bf16 33.5 MB
__device__ float g_decayC[BATCH * NHEADS * NCHUNK];
__device__ short g_Winb[(size_t)NPAD * DMODEL];     // bf16 W_in, zero-padded rows
__device__ short g_Woutb[(size_t)DMODEL * DINNER];  // bf16 W_out

__device__ __forceinline__ short f2bf(float f) {
    unsigned u = __float_as_uint(f);
    u += 0x7fff + ((u >> 16) & 1);
    return (short)(u >> 16);
}
__device__ __forceinline__ float bf2f(short s) {
    return __uint_as_float(((unsigned)(unsigned short)s) << 16);
}

__device__ __forceinline__ void stage16(const void* gsrc, void* ldst) {
    __builtin_amdgcn_global_load_lds(
        (const __attribute__((address_space(1))) void*)gsrc,
        (__attribute__((address_space(3))) void*)ldst, 16, 0, 0);
}

// ---------------- weight convert: fp32 -> bf16 with flat zero-pad tail ----------------
__global__ __launch_bounds__(256) void convert_bf16_kernel(const float* __restrict__ src,
                                                           short* __restrict__ dst,
                                                           int n_valid, int n_total) {
    const int i = blockIdx.x * 256 + threadIdx.x;
    if (i < n_total) dst[i] = (i < n_valid) ? f2bf(src[i]) : (short)0;
}

// ---------------- rmsnorm of x (D=256) -> bf16 xn AND exact fp32 dt (8 heads) ----------
__global__ __launch_bounds__(256) void rmsnorm_dt_kernel(const float* __restrict__ x,
                                                         const float* __restrict__ w,
                                                         const float* __restrict__ W_in,
                                                         short* __restrict__ xn,
                                                         float* __restrict__ dt) {
    const int row  = blockIdx.x * 4 + (threadIdx.x >> 6);
    const int lane = threadIdx.x & 63;
    const float4 v = *(const float4*)(x + (size_t)row * DMODEL + lane * 4);
    float ss = v.x * v.x + v.y * v.y + v.z * v.z + v.w * v.w;
#pragma unroll
    for (int off = 1; off < 64; off <<= 1) ss += __shfl_xor(ss, off);
    const float rs = rsqrtf(ss * (1.0f / DMODEL) + 1.1920929e-7f);
    const float4 wv = *(const float4*)(w + lane * 4);
    const float4 xn4 = make_float4(v.x * rs * wv.x, v.y * rs * wv.y,
                                   v.z * rs * wv.z, v.w * rs * wv.w);
    short4 o;
    o.x = f2bf(xn4.x); o.y = f2bf(xn4.y); o.z = f2bf(xn4.z); o.w = f2bf(xn4.w);
    *(short4*)(xn + (size_t)row * DMODEL + lane * 4) = o;
#pragma unroll
    for (int h = 0; h < NHEADS; ++h) {
        const float4 ww = *(const float4*)(W_in + (size_t)(DPROJ - NHEADS + h) * DMODEL + lane * 4);
        float p = xn4.x * ww.x + xn4.y * ww.y + xn4.z * ww.z + xn4.w * ww.w;
#pragma unroll
        for (int off = 1; off < 64; off <<= 1) p += __shfl_xor(p, off);
        if (lane == 0) dt[(size_t)row * NHEADS + h] = p;
    }
}

// ---------------- bf16 MFMA GEMM: C[M][N] = A[M][K] * B[N][K]^T ----------
// BK=64, XCD-chunked grid swizzle, B-row permute for packed stores, and
// chunk-XOR LDS swizzle (chunk' = chunk ^ (row&7)) applied on BOTH the
// global source address (pre-swizzle, legal for global_load_lds) and the
// ds_read offset -> conflict-free b128 fragment reads at 128B row stride.
template <bool RES, typename OUT>
__global__ __launch_bounds__(256) void gemm_bf16_nt(const short* __restrict__ A,
                                                    const short* __restrict__ B,
                                                    const float* __restrict__ R,
                                                    OUT* __restrict__ C,
                                                    int NX, int M, int N, int K) {
    const int L   = blockIdx.x;
    const int xcd = L & 7;
    const int r   = L >> 3;
    const int mstrips_per_xcd = (M / 128) >> 3;
    const int mblk = xcd * mstrips_per_xcd + r / NX;
    const int nblk = r % NX;
    const int m0 = mblk * 128, n0 = nblk * 128;

    __shared__ __align__(16) short Asl[128 * 64];   // 16 KB
    __shared__ __align__(16) short Bsl[128 * 64];   // 16 KB
    const int tid  = threadIdx.x;
    const int lane = tid & 63;
    const int wid  = tid >> 6;
    const int wrow = (wid >> 1) * 64, wcol = (wid & 1) * 64;

    f32x4 acc[4][4];
#pragma unroll
    for (int m = 0; m < 4; ++m)
#pragma unroll
        for (int n = 0; n < 4; ++n) acc[m][n] = (f32x4)0.f;

    const int wbase = (tid & 0xC0) * 8;             // wave-uniform LDS elem base

    for (int k0 = 0; k0 < K; k0 += 64) {
#pragma unroll
        for (int rr = 0; rr < 4; ++rr) {
            const int idx = rr * 256 + tid;         // 0..1023
            const int row = idx >> 3;               // LDS slot row 0..127
            const int cs  = idx & 7;                // chunk slot 0..7
            const int ko  = (cs ^ (row & 7)) * 8;   // pre-swizzled source chunk
            const int r6  = row & 63;
            const int brow = (row & 64) + (((r6 & 15) << 2) | (r6 >> 4));  // store permute
            stage16(A + (size_t)(m0 + row) * K + k0 + ko, Asl + rr * 2048 + wbase);
            stage16(B + (size_t)(n0 + brow) * K + k0 + ko, Bsl + rr * 2048 + wbase);
        }
        __syncthreads();
#pragma unroll
        for (int ks = 0; ks < 2; ++ks) {
            bf16x8 af[4], bfr[4];
#pragma unroll
            for (int m = 0; m < 4; ++m) {
                const int arow = wrow + m * 16 + (lane & 15);
                const int ch = (ks * 4 + (lane >> 4)) ^ (arow & 7);
                af[m] = *(const bf16x8*)(Asl + arow * 64 + ch * 8);
            }
#pragma unroll
            for (int n = 0; n < 4; ++n) {
                const int brw = wcol + n * 16 + (lane & 15);
                const int ch = (ks * 4 + (lane >> 4)) ^ (brw & 7);
                bfr[n] = *(const bf16x8*)(Bsl + brw * 64 + ch * 8);
            }
#pragma unroll
            for (int m = 0; m < 4; ++m)
#pragma unroll
                for (int n = 0; n < 4; ++n)
                    acc[m][n] = __builtin_amdgcn_mfma_f32_16x16x32_bf16(af[m], bfr[n], acc[m][n], 0, 0, 0);
        }
        __syncthreads();
    }

    // acc[m][n] lane (hi=lane>>4, j=lane&15) holds C[m0+wrow+m*16+hi*4+reg][n0+wcol+4j+n]
    const int r0 = (lane >> 4) * 4;
    const int gcol = n0 + wcol + (lane & 15) * 4;
#pragma unroll
    for (int m = 0; m < 4; ++m) {
        const int grow = m0 + wrow + m * 16 + r0;
        if (gcol < N) {
#pragma unroll
            for (int reg = 0; reg < 4; ++reg) {
                if constexpr (sizeof(OUT) == 2) {
                    short4 o;
                    o.x = f2bf(acc[m][0][reg]); o.y = f2bf(acc[m][1][reg]);
                    o.z = f2bf(acc[m][2][reg]); o.w = f2bf(acc[m][3][reg]);
                    *(short4*)(C + (size_t)(grow + reg) * N + gcol) = o;
                } else {
                    f32x4 v;
                    v[0] = acc[m][0][reg]; v[1] = acc[m][1][reg];
                    v[2] = acc[m][2][reg]; v[3] = acc[m][3][reg];
                    if (RES) v += *(const f32x4*)(R + (size_t)(grow + reg) * N + gcol);
                    *(f32x4*)(C + (size_t)(grow + reg) * N + gcol) = v;
                }
            }
        }
    }
}

// ---- depthwise causal conv(4) + bias + SiLU: sliding window, 4 rows x 8 ch per thread ----
__global__ __launch_bounds__(256) void conv_silu_kernel(const short* __restrict__ zxb,
                                                        const float* __restrict__ cw,
                                                        const float* __restrict__ cb,
                                                        short* __restrict__ xbc) {
    const int idx = blockIdx.x * 256 + threadIdx.x;   // over (NROWS/4)*80
    const int c8  = (idx % 80) * 8;
    const int bl0 = (idx / 80) * 4;                   // first of 4 rows
    const int l0  = bl0 & (SEQ - 1);
    const short* src = zxb + (size_t)bl0 * DPROJ + DINNER + c8;

    float4 w4[8];
    float bias[8];
#pragma unroll
    for (int j = 0; j < 8; ++j) w4[j] = *(const float4*)(cw + (c8 + j) * 4);
    {
        const float4 b0 = *(const float4*)(cb + c8);
        const float4 b1 = *(const float4*)(cb + c8 + 4);
        bias[0] = b0.x; bias[1] = b0.y; bias[2] = b0.z; bias[3] = b0.w;
        bias[4] = b1.x; bias[5] = b1.y; bias[6] = b1.z; bias[7] = b1.w;
    }

    bf16x8 rowv[7];                                   // rows l0-3 .. l0+3
#pragma unroll
    for (int m = 0; m < 7; ++m) {
        if (l0 + m - 3 >= 0)
            rowv[m] = *(const bf16x8*)(src + (ptrdiff_t)(m - 3) * DPROJ);
        else
            rowv[m] = (bf16x8)0;
    }

#pragma unroll
    for (int r = 0; r < 4; ++r) {
        float acc[8];
#pragma unroll
        for (int j = 0; j < 8; ++j) acc[j] = bias[j];
#pragma unroll
        for (int k = 0; k < 4; ++k) {
            const bf16x8 tap = rowv[r + k];
#pragma unroll
            for (int j = 0; j < 8; ++j)
                acc[j] = fmaf(bf2f(tap[j]), ((const float*)&w4[j])[k], acc[j]);
        }
        short8v o;
#pragma unroll
        for (int j = 0; j < 8; ++j) {
            const float s = acc[j];
            o[j] = f2bf(s / (1.f + __expf(-s)));
        }
        *(short8v*)(xbc + (size_t)(bl0 + r) * CONVDIM + c8) = o;
    }
}

// ---------------- scan pass 1 (MFMA): L[p][n] = sum_t X[t][p] * (w_t * B[t][n]) ----------
// BT slot rows permuted (slot n*16+j holds state-col 4j+n) -> packed short4 stores.
__global__ __launch_bounds__(256) void chunk_state_mfma(const float* __restrict__ dt,
                                                        const short* __restrict__ xbc,
                                                        const float* __restrict__ dt_bias,
                                                        const float* __restrict__ A_log,
                                                        short* __restrict__ lstate,
                                                        float* __restrict__ decayC) {
    const int bhc = blockIdx.x;
    const int c = bhc & (NCHUNK - 1), bh = bhc >> 6, h = bh & (NHEADS - 1), b = bh >> 3;
    const int tid = threadIdx.x, lane = tid & 63, wid = tid >> 6;
    __shared__ short XT[64 * LSTR];   // XT[p][t]
    __shared__ short BT[64 * LSTR];   // (w*B)^T, slot-permuted
    __shared__ float wsh[CHUNK];
    const size_t row0 = (size_t)b * SEQ + (size_t)c * CHUNK;

    const float aneg  = -__expf(A_log[h]);
    const float dbias = dt_bias[h];
    if (tid < 64) {
        const float draw = dt[(row0 + tid) * NHEADS + h] + dbias;
        const float dtv  = (draw > 20.f) ? draw : log1pf(__expf(draw));
        float cum = aneg * dtv;
#pragma unroll
        for (int off = 1; off < 64; off <<= 1) {
            const float nv = __shfl_up(cum, off);
            if (lane >= off) cum += nv;
        }
        const float total = __shfl(cum, 63);
        wsh[tid] = __expf(total - cum) * dtv;
        if (tid == 63) decayC[bhc] = __expf(cum);
    }
    __syncthreads();

#pragma unroll
    for (int r = 0; r < 4; ++r) {
        const int idx  = tid + r * 256;
        const int trow = idx >> 4;
        const int q    = idx & 15;                 // channel group: channels 4q..4q+3
        const int c4   = q * 4;
        const short* rp = xbc + (row0 + trow) * CONVDIM;
        const short4 xv = *(const short4*)(rp + h * 64 + c4);
        const short4 bv = *(const short4*)(rp + DINNER + c4);
        const float w = wsh[trow];
        XT[(c4 + 0) * LSTR + trow] = xv.x;
        XT[(c4 + 1) * LSTR + trow] = xv.y;
        XT[(c4 + 2) * LSTR + trow] = xv.z;
        XT[(c4 + 3) * LSTR + trow] = xv.w;
        // channel c4+i -> slot (i*16 + q)
        BT[(0 * 16 + q) * LSTR + trow] = f2bf(bf2f(bv.x) * w);
        BT[(1 * 16 + q) * LSTR + trow] = f2bf(bf2f(bv.y) * w);
        BT[(2 * 16 + q) * LSTR + trow] = f2bf(bf2f(bv.z) * w);
        BT[(3 * 16 + q) * LSTR + trow] = f2bf(bf2f(bv.w) * w);
    }
    __syncthreads();

    f32x4 acc[4];
#pragma unroll
    for (int n = 0; n < 4; ++n) acc[n] = (f32x4)0.f;
#pragma unroll
    for (int ks = 0; ks < 2; ++ks) {
        const bf16x8 af = *(const bf16x8*)(XT + (wid * 16 + (lane & 15)) * LSTR + ks * 32 + (lane >> 4) * 8);
#pragma unroll
        for (int n = 0; n < 4; ++n) {
            const bf16x8 bfv = *(const bf16x8*)(BT + (n * 16 + (lane & 15)) * LSTR + ks * 32 + (lane >> 4) * 8);
            acc[n] = __builtin_amdgcn_mfma_f32_16x16x32_bf16(af, bfv, acc[n], 0, 0, 0);
        }
    }
    // acc[n] lane (hi,j) = L[wid*16+hi*4+reg][4j+n] -> packed short4
    short* lp = lstate + ((size_t)bhc << 12);
    const int ncol = (lane & 15) * 4;
#pragma unroll
    for (int reg = 0; reg < 4; ++reg) {
        const int p = wid * 16 + (lane >> 4) * 4 + reg;
        short4 o;
        o.x = f2bf(acc[0][reg]); o.y = f2bf(acc[1][reg]);
        o.z = f2bf(acc[2][reg]); o.w = f2bf(acc[3][reg]);
        *(short4*)(lp + p * 64 + ncol) = o;
    }
}

// ---------------- scan pass 2: inter-chunk recurrence (bf16 lstate, fp32 carry) --------
__global__ __launch_bounds__(256) void state_prefix_kernel(short* __restrict__ lstate,
                                                           const float* __restrict__ decayC) {
    const int idx = blockIdx.x * 256 + threadIdx.x;   // over BATCH*NHEADS*4096
    const int bh = idx >> 12;
    const int pn = idx & 4095;
    float S = 0.f;
    for (int c = 0; c < NCHUNK; ++c) {
        short* ptr = lstate + (((size_t)bh * NCHUNK + c) << 12) + pn;
        const float l = bf2f(*ptr);
        *ptr = f2bf(S);
        S = fmaf(S, decayC[bh * NCHUNK + c], l);
    }
}

// ---- scan pass 3 (MFMA): Y = mask(C@B^T)@X + exp(cum)*(C@SP^T) + Dp*X; y (bf16) in place --
// XT/SP slot rows permuted (slot pf*16+j holds p-row 4j+pf) -> packed short4 y stores.
__global__ __launch_bounds__(256) void chunk_scan_mfma(const float* __restrict__ dt,
                                                       short* __restrict__ xbc,
                                                       const float* __restrict__ dt_bias,
                                                       const float* __restrict__ A_log,
                                                       const float* __restrict__ Dp,
                                                       const short* __restrict__ lstate) {
    const int bhc = blockIdx.x;
    const int c = bhc & (NCHUNK - 1), bh = bhc >> 6, h = bh & (NHEADS - 1), b = bh >> 3;
    const int tid = threadIdx.x, lane = tid & 63, wid = tid >> 6;
    __shared__ short Bs[64 * LSTR];   // B rows [t][n]
    __shared__ short Cs[64 * LSTR];   // C rows [s][n]
    __shared__ short XT[64 * LSTR];   // X^T, slot-permuted
    __shared__ short SP[64 * LSTR];   // prefix state, slot-permuted
    __shared__ short Ms[64 * LSTR];   // masked scores rows [s][t]
    __shared__ float cums[CHUNK];
    __shared__ float dtss[CHUNK];
    const size_t row0 = (size_t)b * SEQ + (size_t)c * CHUNK;

#pragma unroll
    for (int r = 0; r < 4; ++r) {
        const int idx  = tid + r * 256;
        const int trow = idx >> 4;
        const int q    = idx & 15;
        const int c4   = q * 4;
        const short* rp = xbc + (row0 + trow) * CONVDIM;
        const short4 xv = *(const short4*)(rp + h * 64 + c4);
        *(short4*)(Bs + trow * LSTR + c4) = *(const short4*)(rp + DINNER + c4);
        *(short4*)(Cs + trow * LSTR + c4) = *(const short4*)(rp + DINNER + DSTATE + c4);
        // p-row c4+i -> slot (i*16 + q)
        XT[(0 * 16 + q) * LSTR + trow] = xv.x;
        XT[(1 * 16 + q) * LSTR + trow] = xv.y;
        XT[(2 * 16 + q) * LSTR + trow] = xv.z;
        XT[(3 * 16 + q) * LSTR + trow] = xv.w;
    }
#pragma unroll
    for (int r = 0; r < 4; ++r) {
        const int idx = tid + r * 256;
        const int p = idx >> 4, n4 = (idx & 15) * 4;
        const int pslot = ((p & 3) << 4) | (p >> 2);
        *(short4*)(SP + pslot * LSTR + n4) =
            *(const short4*)(lstate + ((size_t)bhc << 12) + p * 64 + n4);
    }
    const float aneg  = -__expf(A_log[h]);
    const float dbias = dt_bias[h];
    if (tid < 64) {
        const float draw = dt[(row0 + tid) * NHEADS + h] + dbias;
        const float dtv  = (draw > 20.f) ? draw : log1pf(__expf(draw));
        float cum = aneg * dtv;
#pragma unroll
        for (int off = 1; off < 64; off <<= 1) {
            const float nv = __shfl_up(cum, off);
            if (lane >= off) cum += nv;
        }
        cums[tid] = cum;
        dtss[tid] = dtv;
    }
    __syncthreads();

    // G = C @ B^T (over n)
    f32x4 accG[4];
#pragma unroll
    for (int tf = 0; tf < 4; ++tf) accG[tf] = (f32x4)0.f;
#pragma unroll
    for (int ks = 0; ks < 2; ++ks) {
        const bf16x8 af = *(const bf16x8*)(Cs + (wid * 16 + (lane & 15)) * LSTR + ks * 32 + (lane >> 4) * 8);
#pragma unroll
        for (int tf = 0; tf < 4; ++tf) {
            const bf16x8 bfv = *(const bf16x8*)(Bs + (tf * 16 + (lane & 15)) * LSTR + ks * 32 + (lane >> 4) * 8);
            accG[tf] = __builtin_amdgcn_mfma_f32_16x16x32_bf16(af, bfv, accG[tf], 0, 0, 0);
        }
    }
    // causal mask + decay scale -> Ms (bf16)
    const int srow0 = wid * 16 + (lane >> 4) * 4;
#pragma unroll
    for (int tf = 0; tf < 4; ++tf) {
        const int t = tf * 16 + (lane & 15);
        const float ct  = cums[t];
        const float dtt = dtss[t];
#pragma unroll
        for (int reg = 0; reg < 4; ++reg) {
            const int s = srow0 + reg;
            const float m = (t <= s) ? accG[tf][reg] * __expf(cums[s] - ct) * dtt : 0.f;
            Ms[s * LSTR + t] = f2bf(m);
        }
    }
    __syncthreads();

    // Y1 = M @ X ; Y2 = C @ SP^T  (B-operands slot-permuted: pos j of frag pf = p-row 4j+pf)
    f32x4 acc1[4], acc2[4];
#pragma unroll
    for (int pf = 0; pf < 4; ++pf) { acc1[pf] = (f32x4)0.f; acc2[pf] = (f32x4)0.f; }
#pragma unroll
    for (int ks = 0; ks < 2; ++ks) {
        const bf16x8 am = *(const bf16x8*)(Ms + (wid * 16 + (lane & 15)) * LSTR + ks * 32 + (lane >> 4) * 8);
        const bf16x8 ac = *(const bf16x8*)(Cs + (wid * 16 + (lane & 15)) * LSTR + ks * 32 + (lane >> 4) * 8);
#pragma unroll
        for (int pf = 0; pf < 4; ++pf) {
            const bf16x8 bx = *(const bf16x8*)(XT + (pf * 16 + (lane & 15)) * LSTR + ks * 32 + (lane >> 4) * 8);
            const bf16x8 bs = *(const bf16x8*)(SP + (pf * 16 + (lane & 15)) * LSTR + ks * 32 + (lane >> 4) * 8);
            acc1[pf] = __builtin_amdgcn_mfma_f32_16x16x32_bf16(am, bx, acc1[pf], 0, 0, 0);
            acc2[pf] = __builtin_amdgcn_mfma_f32_16x16x32_bf16(ac, bs, acc2[pf], 0, 0, 0);
        }
    }
    const float dpv = Dp[h];
    float es[4];
#pragma unroll
    for (int reg = 0; reg < 4; ++reg) es[reg] = __expf(cums[srow0 + reg]);
    // acc1/acc2[pf] lane (hi,j): Y[srow0+reg][p = 4j+pf]; XT slot of p=4j+pf is pf*16+j
    const int j = lane & 15;
#pragma unroll
    for (int reg = 0; reg < 4; ++reg) {
        const int s = srow0 + reg;
        short4 o;
#pragma unroll
        for (int pf = 0; pf < 4; ++pf) {
            const float xv = bf2f(XT[(pf * 16 + j) * LSTR + s]);
            const float yv = acc1[pf][reg] + es[reg] * acc2[pf][reg] + dpv * xv;
            ((short*)&o)[pf] = f2bf(yv);
        }
        *(short4*)(xbc + (row0 + s) * CONVDIM + h * 64 + j * 4) = o;
    }
}

// ---------------- y(bf16)*silu(z) -> rmsnorm (D=512) -> bf16 yzn ----------------
__global__ __launch_bounds__(256) void gate_norm_kernel(const short* __restrict__ xbc,
                                                        const short* __restrict__ zxb,
                                                        const float* __restrict__ gw,
                                                        short* __restrict__ yzn) {
    const int row  = blockIdx.x * 4 + (threadIdx.x >> 6);
    const int lane = threadIdx.x & 63;
    const bf16x8 yv8 = *(const bf16x8*)(xbc + (size_t)row * CONVDIM + lane * 8);
    const bf16x8 zv  = *(const bf16x8*)(zxb + (size_t)row * DPROJ + lane * 8);
    float v[8];
#pragma unroll
    for (int i = 0; i < 8; ++i) {
        const float z = bf2f(zv[i]);
        v[i] = bf2f(yv8[i]) * z / (1.f + __expf(-z));
    }
    float ss = 0.f;
#pragma unroll
    for (int i = 0; i < 8; ++i) ss += v[i] * v[i];
#pragma unroll
    for (int off = 1; off < 64; off <<= 1) ss += __shfl_xor(ss, off);
    const float rs = rsqrtf(ss * (1.0f / DINNER) + 1e-5f);
    const float* g = gw + lane * 8;
    short8v o;
#pragma unroll
    for (int i = 0; i < 8; ++i) o[i] = f2bf(v[i] * rs * g[i]);
    *(short8v*)(yzn + (size_t)row * DINNER + lane * 8) = o;
}

// ---------------- launch ----------------
extern "C" void kernel_launch(void* const* d_in, const int* in_sizes, int n_in,
                              void* d_out, int out_size, void* d_ws, size_t ws_size,
                              hipStream_t stream) {
    (void)in_sizes; (void)n_in; (void)out_size; (void)d_ws; (void)ws_size;
    const float* x      = (const float*)d_in[0];
    const float* W_in   = (const float*)d_in[1];
    const float* conv_w = (const float*)d_in[2];
    const float* conv_b = (const float*)d_in[3];
    const float* dt_b   = (const float*)d_in[4];
    const float* A_log  = (const float*)d_in[5];
    const float* Dp     = (const float*)d_in[6];
    const float* g_w    = (const float*)d_in[7];
    const float* n_w    = (const float*)d_in[8];
    const float* W_out  = (const float*)d_in[9];
    float* out = (float*)d_out;

    short *xn, *zxb, *xbc, *yzn, *winb, *woutb, *lst;
    float *dtv, *dcy;
    hipGetSymbolAddress((void**)&xn,    HIP_SYMBOL(g_xn));
    hipGetSymbolAddress((void**)&zxb,   HIP_SYMBOL(g_zxb));
    hipGetSymbolAddress((void**)&xbc,   HIP_SYMBOL(g_xbc));
    hipGetSymbolAddress((void**)&dtv,   HIP_SYMBOL(g_dt));
    hipGetSymbolAddress((void**)&yzn,   HIP_SYMBOL(g_yzn));
    hipGetSymbolAddress((void**)&lst,   HIP_SYMBOL(g_lstate));
    hipGetSymbolAddress((void**)&dcy,   HIP_SYMBOL(g_decayC));
    hipGetSymbolAddress((void**)&winb,  HIP_SYMBOL(g_Winb));
    hipGetSymbolAddress((void**)&woutb, HIP_SYMBOL(g_Woutb));

    convert_bf16_kernel<<<(NPAD * DMODEL) / 256, 256, 0, stream>>>(
        W_in, winb, DPROJ * DMODEL, NPAD * DMODEL);
    convert_bf16_kernel<<<(DMODEL * DINNER) / 256, 256, 0, stream>>>(
        W_out, woutb, DMODEL * DINNER, DMODEL * DINNER);

    rmsnorm_dt_kernel<<<NROWS / 4, 256, 0, stream>>>(x, n_w, W_in, xn, dtv);

    gemm_bf16_nt<false, short><<<(NPAD / 128) * (NROWS / 128), 256, 0, stream>>>(
        xn, winb, nullptr, zxb, NPAD / 128, NROWS, DPROJ, DMODEL);

    conv_silu_kernel<<<(NROWS / 4 * 80) / 256, 256, 0, stream>>>(zxb, conv_w, conv_b, xbc);

    chunk_state_mfma<<<BATCH * NHEADS * NCHUNK, 256, 0, stream>>>(dtv, xbc, dt_b, A_log, lst, dcy);
    state_prefix_kernel<<<(BATCH * NHEADS * HEADDIM * DSTATE) / 256, 256, 0, stream>>>(lst, dcy);
    chunk_scan_mfma<<<BATCH * NHEADS * NCHUNK, 256, 0, stream>>>(dtv, xbc, dt_b, A_log, Dp, lst);

    gate_norm_kernel<<<NROWS / 4, 256, 0, stream>>>(xbc, zxb, g_w, yzn);

    gemm_bf16_nt<true, float><<<(DMODEL / 128) * (NROWS / 128), 256, 0, stream>>>(
        yzn, woutb, x, out, DMODEL / 128, NROWS, DMODEL, DINNER);
}

// Round 11
// 188.354 us; speedup vs baseline: 1.2491x; 1.0287x over previous
//
#include <hip/hip_runtime.h>
#include <math.h>

#define BATCH   8
#define SEQ     4096
#define DMODEL  256
#define DINNER  512
#define DSTATE  64
#define NHEADS  8
#define HEADDIM 64
#define CONVDIM 640          // DINNER + 2*DSTATE
#define DPROJ   1160         // 2*DINNER + 2*DSTATE + NHEADS
#define NROWS   (BATCH*SEQ)  // 32768
#define CHUNK   64
#define NCHUNK  (SEQ/CHUNK)  // 64
#define NPAD    1280         // DPROJ padded to mult of 128 for bf16 W_in
#define LSTR    72           // LDS row stride (shorts)

typedef short bf16x8 __attribute__((ext_vector_type(8)));
typedef short short8v __attribute__((ext_vector_type(8)));
typedef float f32x4 __attribute__((ext_vector_type(4)));

// ---- static workspace (BSS) ----
__device__ short g_xn[(size_t)NROWS * DMODEL];      // bf16 16.8 MB
__device__ short g_zxb[(size_t)NROWS * DPROJ];      // bf16 76.0 MB (z | xBC | unused dt)
__device__ short g_xbc[(size_t)NROWS * CONVDIM];    // bf16 42.0 MB (conv out; x-slice overwritten by gated v)
__device__ float g_dt[(size_t)NROWS * NHEADS];      // fp32  1.0 MB (raw dt, pre-bias)
__device__ float g_rowss[(size_t)NROWS * NHEADS];   // fp32  1.0 MB (per-row per-head sum of v^2)
__device__ short g_lstate[(size_t)BATCH * NHEADS * NCHUNK * HEADDIM * DSTATE]; // bf16 33.5 MB
__device__ float g_decayC[BATCH * NHEADS * NCHUNK];
__device__ short g_Winb[(size_t)NPAD * DMODEL];     // bf16 W_in, zero-padded rows
__device__ short g_Woutb[(size_t)DMODEL * DINNER];  // bf16 W_out * gnorm_w

__device__ __forceinline__ short f2bf(float f) {
    unsigned u = __float_as_uint(f);
    u += 0x7fff + ((u >> 16) & 1);
    return (short)(u >> 16);
}
__device__ __forceinline__ float bf2f(short s) {
    return __uint_as_float(((unsigned)(unsigned short)s) << 16);
}

__device__ __forceinline__ void stage16(const void* gsrc, void* ldst) {
    __builtin_amdgcn_global_load_lds(
        (const __attribute__((address_space(1))) void*)gsrc,
        (__attribute__((address_space(3))) void*)ldst, 16, 0, 0);
}

// ---------------- weight convert: fp32 -> bf16 with flat zero-pad tail ----------------
__global__ __launch_bounds__(256) void convert_bf16_kernel(const float* __restrict__ src,
                                                           short* __restrict__ dst,
                                                           int n_valid, int n_total) {
    const int i = blockIdx.x * 256 + threadIdx.x;
    if (i < n_total) dst[i] = (i < n_valid) ? f2bf(src[i]) : (short)0;
}

// ---------------- W_out convert with gnorm_w folded: dst[d][e] = bf16(W_out[d][e]*g[e]) ----
__global__ __launch_bounds__(256) void convert_wout_kernel(const float* __restrict__ src,
                                                           const float* __restrict__ gw,
                                                           short* __restrict__ dst) {
    const int i = blockIdx.x * 256 + threadIdx.x;
    if (i < DMODEL * DINNER) dst[i] = f2bf(src[i] * gw[i % DINNER]);
}

// ---------------- rmsnorm of x (D=256) -> bf16 xn AND exact fp32 dt (8 heads) ----------
__global__ __launch_bounds__(256) void rmsnorm_dt_kernel(const float* __restrict__ x,
                                                         const float* __restrict__ w,
                                                         const float* __restrict__ W_in,
                                                         short* __restrict__ xn,
                                                         float* __restrict__ dt) {
    const int row  = blockIdx.x * 4 + (threadIdx.x >> 6);
    const int lane = threadIdx.x & 63;
    const float4 v = *(const float4*)(x + (size_t)row * DMODEL + lane * 4);
    float ss = v.x * v.x + v.y * v.y + v.z * v.z + v.w * v.w;
#pragma unroll
    for (int off = 1; off < 64; off <<= 1) ss += __shfl_xor(ss, off);
    const float rs = rsqrtf(ss * (1.0f / DMODEL) + 1.1920929e-7f);
    const float4 wv = *(const float4*)(w + lane * 4);
    const float4 xn4 = make_float4(v.x * rs * wv.x, v.y * rs * wv.y,
                                   v.z * rs * wv.z, v.w * rs * wv.w);
    short4 o;
    o.x = f2bf(xn4.x); o.y = f2bf(xn4.y); o.z = f2bf(xn4.z); o.w = f2bf(xn4.w);
    *(short4*)(xn + (size_t)row * DMODEL + lane * 4) = o;
#pragma unroll
    for (int h = 0; h < NHEADS; ++h) {
        const float4 ww = *(const float4*)(W_in + (size_t)(DPROJ - NHEADS + h) * DMODEL + lane * 4);
        float p = xn4.x * ww.x + xn4.y * ww.y + xn4.z * ww.z + xn4.w * ww.w;
#pragma unroll
        for (int off = 1; off < 64; off <<= 1) p += __shfl_xor(p, off);
        if (lane == 0) dt[(size_t)row * NHEADS + h] = p;
    }
}

// ---------------- bf16 MFMA GEMM: C[M][N] = A[M][K] * B[N][K]^T ----------
// BK=64, XCD-chunked grid swizzle, B-row permute -> packed stores, chunk-XOR
// LDS swizzle both-sides. RES path (GEMM2): per-row rs = rsqrt(sum8(RS)/512+eps)
// applied in epilogue before residual (fused gated-RMSNorm scale).
template <bool RES, typename OUT>
__global__ __launch_bounds__(256) void gemm_bf16_nt(const short* __restrict__ A,
                                                    const short* __restrict__ B,
                                                    const float* __restrict__ R,
                                                    const float* __restrict__ RS,
                                                    OUT* __restrict__ C,
                                                    int NX, int M, int N, int K, int LDA) {
    const int L   = blockIdx.x;
    const int xcd = L & 7;
    const int r   = L >> 3;
    const int mstrips_per_xcd = (M / 128) >> 3;
    const int mblk = xcd * mstrips_per_xcd + r / NX;
    const int nblk = r % NX;
    const int m0 = mblk * 128, n0 = nblk * 128;

    __shared__ __align__(16) short Asl[128 * 64];   // 16 KB
    __shared__ __align__(16) short Bsl[128 * 64];   // 16 KB
    const int tid  = threadIdx.x;
    const int lane = tid & 63;
    const int wid  = tid >> 6;
    const int wrow = (wid >> 1) * 64, wcol = (wid & 1) * 64;

    f32x4 acc[4][4];
#pragma unroll
    for (int m = 0; m < 4; ++m)
#pragma unroll
        for (int n = 0; n < 4; ++n) acc[m][n] = (f32x4)0.f;

    const int wbase = (tid & 0xC0) * 8;             // wave-uniform LDS elem base

    for (int k0 = 0; k0 < K; k0 += 64) {
#pragma unroll
        for (int rr = 0; rr < 4; ++rr) {
            const int idx = rr * 256 + tid;         // 0..1023
            const int row = idx >> 3;               // LDS slot row 0..127
            const int cs  = idx & 7;                // chunk slot 0..7
            const int ko  = (cs ^ (row & 7)) * 8;   // pre-swizzled source chunk
            const int r6  = row & 63;
            const int brow = (row & 64) + (((r6 & 15) << 2) | (r6 >> 4));  // store permute
            stage16(A + (size_t)(m0 + row) * LDA + k0 + ko, Asl + rr * 2048 + wbase);
            stage16(B + (size_t)(n0 + brow) * K + k0 + ko, Bsl + rr * 2048 + wbase);
        }
        __syncthreads();
#pragma unroll
        for (int ks = 0; ks < 2; ++ks) {
            bf16x8 af[4], bfr[4];
#pragma unroll
            for (int m = 0; m < 4; ++m) {
                const int arow = wrow + m * 16 + (lane & 15);
                const int ch = (ks * 4 + (lane >> 4)) ^ (arow & 7);
                af[m] = *(const bf16x8*)(Asl + arow * 64 + ch * 8);
            }
#pragma unroll
            for (int n = 0; n < 4; ++n) {
                const int brw = wcol + n * 16 + (lane & 15);
                const int ch = (ks * 4 + (lane >> 4)) ^ (brw & 7);
                bfr[n] = *(const bf16x8*)(Bsl + brw * 64 + ch * 8);
            }
#pragma unroll
            for (int m = 0; m < 4; ++m)
#pragma unroll
                for (int n = 0; n < 4; ++n)
                    acc[m][n] = __builtin_amdgcn_mfma_f32_16x16x32_bf16(af[m], bfr[n], acc[m][n], 0, 0, 0);
        }
        __syncthreads();
    }

    // acc[m][n] lane (hi=lane>>4, j=lane&15) holds C[m0+wrow+m*16+hi*4+reg][n0+wcol+4j+n]
    const int r0 = (lane >> 4) * 4;
    const int gcol = n0 + wcol + (lane & 15) * 4;
#pragma unroll
    for (int m = 0; m < 4; ++m) {
        const int grow = m0 + wrow + m * 16 + r0;
        if (gcol < N) {
#pragma unroll
            for (int reg = 0; reg < 4; ++reg) {
                if constexpr (sizeof(OUT) == 2) {
                    short4 o;
                    o.x = f2bf(acc[m][0][reg]); o.y = f2bf(acc[m][1][reg]);
                    o.z = f2bf(acc[m][2][reg]); o.w = f2bf(acc[m][3][reg]);
                    *(short4*)(C + (size_t)(grow + reg) * N + gcol) = o;
                } else {
                    f32x4 v;
                    v[0] = acc[m][0][reg]; v[1] = acc[m][1][reg];
                    v[2] = acc[m][2][reg]; v[3] = acc[m][3][reg];
                    if (RES) {
                        const float* rp = RS + (size_t)(grow + reg) * NHEADS;
                        const f32x4 s0 = *(const f32x4*)rp;
                        const f32x4 s1 = *(const f32x4*)(rp + 4);
                        const float sum = s0[0] + s0[1] + s0[2] + s0[3] +
                                          s1[0] + s1[1] + s1[2] + s1[3];
                        const float rsn = rsqrtf(sum * (1.0f / DINNER) + 1e-5f);
                        v *= rsn;
                        v += *(const f32x4*)(R + (size_t)(grow + reg) * N + gcol);
                    }
                    *(f32x4*)(C + (size_t)(grow + reg) * N + gcol) = v;
                }
            }
        }
    }
}

// ---- depthwise causal conv(4) + bias + SiLU: sliding window, 8 rows x 8 ch per thread ----
__global__ __launch_bounds__(256) void conv_silu_kernel(const short* __restrict__ zxb,
                                                        const float* __restrict__ cw,
                                                        const float* __restrict__ cb,
                                                        short* __restrict__ xbc) {
    const int idx = blockIdx.x * 256 + threadIdx.x;   // over (NROWS/8)*80
    const int c8  = (idx % 80) * 8;
    const int bl0 = (idx / 80) * 8;                   // first of 8 rows
    const int l0  = bl0 & (SEQ - 1);
    const short* src = zxb + (size_t)bl0 * DPROJ + DINNER + c8;

    float4 w4[8];
    float bias[8];
#pragma unroll
    for (int j = 0; j < 8; ++j) w4[j] = *(const float4*)(cw + (c8 + j) * 4);
    {
        const float4 b0 = *(const float4*)(cb + c8);
        const float4 b1 = *(const float4*)(cb + c8 + 4);
        bias[0] = b0.x; bias[1] = b0.y; bias[2] = b0.z; bias[3] = b0.w;
        bias[4] = b1.x; bias[5] = b1.y; bias[6] = b1.z; bias[7] = b1.w;
    }

    bf16x8 rowv[11];                                  // rows l0-3 .. l0+7
#pragma unroll
    for (int m = 0; m < 11; ++m) {
        if (l0 + m - 3 >= 0)
            rowv[m] = *(const bf16x8*)(src + (ptrdiff_t)(m - 3) * DPROJ);
        else
            rowv[m] = (bf16x8)0;
    }

#pragma unroll
    for (int r = 0; r < 8; ++r) {
        float acc[8];
#pragma unroll
        for (int j = 0; j < 8; ++j) acc[j] = bias[j];
#pragma unroll
        for (int k = 0; k < 4; ++k) {
            const bf16x8 tap = rowv[r + k];
#pragma unroll
            for (int j = 0; j < 8; ++j)
                acc[j] = fmaf(bf2f(tap[j]), ((const float*)&w4[j])[k], acc[j]);
        }
        short8v o;
#pragma unroll
        for (int j = 0; j < 8; ++j) {
            const float s = acc[j];
            o[j] = f2bf(s / (1.f + __expf(-s)));
        }
        *(short8v*)(xbc + (size_t)(bl0 + r) * CONVDIM + c8) = o;
    }
}

// ---------------- scan pass 1 (MFMA): L[p][n] = sum_t X[t][p] * (w_t * B[t][n]) ----------
__global__ __launch_bounds__(256) void chunk_state_mfma(const float* __restrict__ dt,
                                                        const short* __restrict__ xbc,
                                                        const float* __restrict__ dt_bias,
                                                        const float* __restrict__ A_log,
                                                        short* __restrict__ lstate,
                                                        float* __restrict__ decayC) {
    const int bhc = blockIdx.x;
    const int c = bhc & (NCHUNK - 1), bh = bhc >> 6, h = bh & (NHEADS - 1), b = bh >> 3;
    const int tid = threadIdx.x, lane = tid & 63, wid = tid >> 6;
    __shared__ short XT[64 * LSTR];   // XT[p][t]
    __shared__ short BT[64 * LSTR];   // (w*B)^T, slot-permuted
    __shared__ float wsh[CHUNK];
    const size_t row0 = (size_t)b * SEQ + (size_t)c * CHUNK;

    const float aneg  = -__expf(A_log[h]);
    const float dbias = dt_bias[h];
    if (tid < 64) {
        const float draw = dt[(row0 + tid) * NHEADS + h] + dbias;
        const float dtv  = (draw > 20.f) ? draw : log1pf(__expf(draw));
        float cum = aneg * dtv;
#pragma unroll
        for (int off = 1; off < 64; off <<= 1) {
            const float nv = __shfl_up(cum, off);
            if (lane >= off) cum += nv;
        }
        const float total = __shfl(cum, 63);
        wsh[tid] = __expf(total - cum) * dtv;
        if (tid == 63) decayC[bhc] = __expf(cum);
    }
    __syncthreads();

#pragma unroll
    for (int r = 0; r < 4; ++r) {
        const int idx  = tid + r * 256;
        const int trow = idx >> 4;
        const int q    = idx & 15;                 // channel group: channels 4q..4q+3
        const int c4   = q * 4;
        const short* rp = xbc + (row0 + trow) * CONVDIM;
        const short4 xv = *(const short4*)(rp + h * 64 + c4);
        const short4 bv = *(const short4*)(rp + DINNER + c4);
        const float w = wsh[trow];
        XT[(c4 + 0) * LSTR + trow] = xv.x;
        XT[(c4 + 1) * LSTR + trow] = xv.y;
        XT[(c4 + 2) * LSTR + trow] = xv.z;
        XT[(c4 + 3) * LSTR + trow] = xv.w;
        // channel c4+i -> slot (i*16 + q)
        BT[(0 * 16 + q) * LSTR + trow] = f2bf(bf2f(bv.x) * w);
        BT[(1 * 16 + q) * LSTR + trow] = f2bf(bf2f(bv.y) * w);
        BT[(2 * 16 + q) * LSTR + trow] = f2bf(bf2f(bv.z) * w);
        BT[(3 * 16 + q) * LSTR + trow] = f2bf(bf2f(bv.w) * w);
    }
    __syncthreads();

    f32x4 acc[4];
#pragma unroll
    for (int n = 0; n < 4; ++n) acc[n] = (f32x4)0.f;
#pragma unroll
    for (int ks = 0; ks < 2; ++ks) {
        const bf16x8 af = *(const bf16x8*)(XT + (wid * 16 + (lane & 15)) * LSTR + ks * 32 + (lane >> 4) * 8);
#pragma unroll
        for (int n = 0; n < 4; ++n) {
            const bf16x8 bfv = *(const bf16x8*)(BT + (n * 16 + (lane & 15)) * LSTR + ks * 32 + (lane >> 4) * 8);
            acc[n] = __builtin_amdgcn_mfma_f32_16x16x32_bf16(af, bfv, acc[n], 0, 0, 0);
        }
    }
    // acc[n] lane (hi,j) = L[wid*16+hi*4+reg][4j+n] -> packed short4
    short* lp = lstate + ((size_t)bhc << 12);
    const int ncol = (lane & 15) * 4;
#pragma unroll
    for (int reg = 0; reg < 4; ++reg) {
        const int p = wid * 16 + (lane >> 4) * 4 + reg;
        short4 o;
        o.x = f2bf(acc[0][reg]); o.y = f2bf(acc[1][reg]);
        o.z = f2bf(acc[2][reg]); o.w = f2bf(acc[3][reg]);
        *(short4*)(lp + p * 64 + ncol) = o;
    }
}

// ---------------- scan pass 2: inter-chunk recurrence (bf16 lstate, fp32 carry) --------
__global__ __launch_bounds__(256) void state_prefix_kernel(short* __restrict__ lstate,
                                                           const float* __restrict__ decayC) {
    const int idx = blockIdx.x * 256 + threadIdx.x;   // over BATCH*NHEADS*4096
    const int bh = idx >> 12;
    const int pn = idx & 4095;
    float S = 0.f;
    for (int c = 0; c < NCHUNK; ++c) {
        short* ptr = lstate + (((size_t)bh * NCHUNK + c) << 12) + pn;
        const float l = bf2f(*ptr);
        *ptr = f2bf(S);
        S = fmaf(S, decayC[bh * NCHUNK + c], l);
    }
}

// ---- scan pass 3 (MFMA): y = mask(C@B^T)@X + exp(cum)*(C@SP^T) + Dp*X, then FUSED
// gating v = y*silu(z) (fp32 y), per-row-per-head sum(v^2) -> rowss, v (bf16) in place. ----
__global__ __launch_bounds__(256) void chunk_scan_mfma(const float* __restrict__ dt,
                                                       short* __restrict__ xbc,
                                                       const short* __restrict__ zxb,
                                                       float* __restrict__ rowss,
                                                       const float* __restrict__ dt_bias,
                                                       const float* __restrict__ A_log,
                                                       const float* __restrict__ Dp,
                                                       const short* __restrict__ lstate) {
    const int bhc = blockIdx.x;
    const int c = bhc & (NCHUNK - 1), bh = bhc >> 6, h = bh & (NHEADS - 1), b = bh >> 3;
    const int tid = threadIdx.x, lane = tid & 63, wid = tid >> 6;
    __shared__ short Bs[64 * LSTR];   // B rows [t][n]
    __shared__ short Cs[64 * LSTR];   // C rows [s][n]
    __shared__ short XT[64 * LSTR];   // X^T, slot-permuted
    __shared__ short SP[64 * LSTR];   // prefix state, slot-permuted
    __shared__ short Ms[64 * LSTR];   // masked scores rows [s][t]
    __shared__ float cums[CHUNK];
    __shared__ float dtss[CHUNK];
    const size_t row0 = (size_t)b * SEQ + (size_t)c * CHUNK;

#pragma unroll
    for (int r = 0; r < 4; ++r) {
        const int idx  = tid + r * 256;
        const int trow = idx >> 4;
        const int q    = idx & 15;
        const int c4   = q * 4;
        const short* rp = xbc + (row0 + trow) * CONVDIM;
        const short4 xv = *(const short4*)(rp + h * 64 + c4);
        *(short4*)(Bs + trow * LSTR + c4) = *(const short4*)(rp + DINNER + c4);
        *(short4*)(Cs + trow * LSTR + c4) = *(const short4*)(rp + DINNER + DSTATE + c4);
        // p-row c4+i -> slot (i*16 + q)
        XT[(0 * 16 + q) * LSTR + trow] = xv.x;
        XT[(1 * 16 + q) * LSTR + trow] = xv.y;
        XT[(2 * 16 + q) * LSTR + trow] = xv.z;
        XT[(3 * 16 + q) * LSTR + trow] = xv.w;
    }
#pragma unroll
    for (int r = 0; r < 4; ++r) {
        const int idx = tid + r * 256;
        const int p = idx >> 4, n4 = (idx & 15) * 4;
        const int pslot = ((p & 3) << 4) | (p >> 2);
        *(short4*)(SP + pslot * LSTR + n4) =
            *(const short4*)(lstate + ((size_t)bhc << 12) + p * 64 + n4);
    }
    const float aneg  = -__expf(A_log[h]);
    const float dbias = dt_bias[h];
    if (tid < 64) {
        const float draw = dt[(row0 + tid) * NHEADS + h] + dbias;
        const float dtv  = (draw > 20.f) ? draw : log1pf(__expf(draw));
        float cum = aneg * dtv;
#pragma unroll
        for (int off = 1; off < 64; off <<= 1) {
            const float nv = __shfl_up(cum, off);
            if (lane >= off) cum += nv;
        }
        cums[tid] = cum;
        dtss[tid] = dtv;
    }
    __syncthreads();

    // G = C @ B^T (over n)
    f32x4 accG[4];
#pragma unroll
    for (int tf = 0; tf < 4; ++tf) accG[tf] = (f32x4)0.f;
#pragma unroll
    for (int ks = 0; ks < 2; ++ks) {
        const bf16x8 af = *(const bf16x8*)(Cs + (wid * 16 + (lane & 15)) * LSTR + ks * 32 + (lane >> 4) * 8);
#pragma unroll
        for (int tf = 0; tf < 4; ++tf) {
            const bf16x8 bfv = *(const bf16x8*)(Bs + (tf * 16 + (lane & 15)) * LSTR + ks * 32 + (lane >> 4) * 8);
            accG[tf] = __builtin_amdgcn_mfma_f32_16x16x32_bf16(af, bfv, accG[tf], 0, 0, 0);
        }
    }
    // causal mask + decay scale -> Ms (bf16)
    const int srow0 = wid * 16 + (lane >> 4) * 4;
#pragma unroll
    for (int tf = 0; tf < 4; ++tf) {
        const int t = tf * 16 + (lane & 15);
        const float ct  = cums[t];
        const float dtt = dtss[t];
#pragma unroll
        for (int reg = 0; reg < 4; ++reg) {
            const int s = srow0 + reg;
            const float m = (t <= s) ? accG[tf][reg] * __expf(cums[s] - ct) * dtt : 0.f;
            Ms[s * LSTR + t] = f2bf(m);
        }
    }
    __syncthreads();

    // Y1 = M @ X ; Y2 = C @ SP^T  (B-operands slot-permuted: pos j of frag pf = p-row 4j+pf)
    f32x4 acc1[4], acc2[4];
#pragma unroll
    for (int pf = 0; pf < 4; ++pf) { acc1[pf] = (f32x4)0.f; acc2[pf] = (f32x4)0.f; }
#pragma unroll
    for (int ks = 0; ks < 2; ++ks) {
        const bf16x8 am = *(const bf16x8*)(Ms + (wid * 16 + (lane & 15)) * LSTR + ks * 32 + (lane >> 4) * 8);
        const bf16x8 ac = *(const bf16x8*)(Cs + (wid * 16 + (lane & 15)) * LSTR + ks * 32 + (lane >> 4) * 8);
#pragma unroll
        for (int pf = 0; pf < 4; ++pf) {
            const bf16x8 bx = *(const bf16x8*)(XT + (pf * 16 + (lane & 15)) * LSTR + ks * 32 + (lane >> 4) * 8);
            const bf16x8 bs = *(const bf16x8*)(SP + (pf * 16 + (lane & 15)) * LSTR + ks * 32 + (lane >> 4) * 8);
            acc1[pf] = __builtin_amdgcn_mfma_f32_16x16x32_bf16(am, bx, acc1[pf], 0, 0, 0);
            acc2[pf] = __builtin_amdgcn_mfma_f32_16x16x32_bf16(ac, bs, acc2[pf], 0, 0, 0);
        }
    }
    const float dpv = Dp[h];
    float es[4];
#pragma unroll
    for (int reg = 0; reg < 4; ++reg) es[reg] = __expf(cums[srow0 + reg]);
    // acc1/acc2[pf] lane (hi,j): Y[srow0+reg][p = 4j+pf]; XT slot of p=4j+pf is pf*16+j
    const int j = lane & 15;
#pragma unroll
    for (int reg = 0; reg < 4; ++reg) {
        const int s = srow0 + reg;
        const short4 z4 = *(const short4*)(zxb + (row0 + s) * DPROJ + h * 64 + j * 4);
        short4 o;
        float ssq = 0.f;
#pragma unroll
        for (int pf = 0; pf < 4; ++pf) {
            const float xv = bf2f(XT[(pf * 16 + j) * LSTR + s]);
            const float yv = acc1[pf][reg] + es[reg] * acc2[pf][reg] + dpv * xv;
            const float zf = bf2f(((const short*)&z4)[pf]);
            const float v  = yv * zf / (1.f + __expf(-zf));
            ((short*)&o)[pf] = f2bf(v);
            ssq = fmaf(v, v, ssq);
        }
        *(short4*)(xbc + (row0 + s) * CONVDIM + h * 64 + j * 4) = o;
        // reduce ssq over the 16 j-lanes of this row
        ssq += __shfl_xor(ssq, 1);
        ssq += __shfl_xor(ssq, 2);
        ssq += __shfl_xor(ssq, 4);
        ssq += __shfl_xor(ssq, 8);
        if (j == 0) rowss[(row0 + s) * NHEADS + h] = ssq;
    }
}

// ---------------- launch ----------------
extern "C" void kernel_launch(void* const* d_in, const int* in_sizes, int n_in,
                              void* d_out, int out_size, void* d_ws, size_t ws_size,
                              hipStream_t stream) {
    (void)in_sizes; (void)n_in; (void)out_size; (void)d_ws; (void)ws_size;
    const float* x      = (const float*)d_in[0];
    const float* W_in   = (const float*)d_in[1];
    const float* conv_w = (const float*)d_in[2];
    const float* conv_b = (const float*)d_in[3];
    const float* dt_b   = (const float*)d_in[4];
    const float* A_log  = (const float*)d_in[5];
    const float* Dp     = (const float*)d_in[6];
    const float* g_w    = (const float*)d_in[7];
    const float* n_w    = (const float*)d_in[8];
    const float* W_out  = (const float*)d_in[9];
    float* out = (float*)d_out;

    short *xn, *zxb, *xbc, *winb, *woutb, *lst;
    float *dtv, *dcy, *rss;
    hipGetSymbolAddress((void**)&xn,    HIP_SYMBOL(g_xn));
    hipGetSymbolAddress((void**)&zxb,   HIP_SYMBOL(g_zxb));
    hipGetSymbolAddress((void**)&xbc,   HIP_SYMBOL(g_xbc));
    hipGetSymbolAddress((void**)&dtv,   HIP_SYMBOL(g_dt));
    hipGetSymbolAddress((void**)&rss,   HIP_SYMBOL(g_rowss));
    hipGetSymbolAddress((void**)&lst,   HIP_SYMBOL(g_lstate));
    hipGetSymbolAddress((void**)&dcy,   HIP_SYMBOL(g_decayC));
    hipGetSymbolAddress((void**)&winb,  HIP_SYMBOL(g_Winb));
    hipGetSymbolAddress((void**)&woutb, HIP_SYMBOL(g_Woutb));

    convert_bf16_kernel<<<(NPAD * DMODEL) / 256, 256, 0, stream>>>(
        W_in, winb, DPROJ * DMODEL, NPAD * DMODEL);
    convert_wout_kernel<<<(DMODEL * DINNER) / 256, 256, 0, stream>>>(W_out, g_w, woutb);

    rmsnorm_dt_kernel<<<NROWS / 4, 256, 0, stream>>>(x, n_w, W_in, xn, dtv);

    gemm_bf16_nt<false, short><<<(NPAD / 128) * (NROWS / 128), 256, 0, stream>>>(
        xn, winb, nullptr, nullptr, zxb, NPAD / 128, NROWS, DPROJ, DMODEL, DMODEL);

    conv_silu_kernel<<<(NROWS / 8 * 80) / 256, 256, 0, stream>>>(zxb, conv_w, conv_b, xbc);

    chunk_state_mfma<<<BATCH * NHEADS * NCHUNK, 256, 0, stream>>>(dtv, xbc, dt_b, A_log, lst, dcy);
    state_prefix_kernel<<<(BATCH * NHEADS * HEADDIM * DSTATE) / 256, 256, 0, stream>>>(lst, dcy);
    chunk_scan_mfma<<<BATCH * NHEADS * NCHUNK, 256, 0, stream>>>(
        dtv, xbc, zxb, rss, dt_b, A_log, Dp, lst);

    gemm_bf16_nt<true, float><<<(DMODEL / 128) * (NROWS / 128), 256, 0, stream>>>(
        xbc, woutb, x, rss, out, DMODEL / 128, NROWS, DMODEL, DINNER, CONVDIM);
}

// Round 12
// 174.847 us; speedup vs baseline: 1.3456x; 1.0772x over previous
//
#include <hip/hip_runtime.h>
#include <math.h>

#define BATCH   8
#define SEQ     4096
#define DMODEL  256
#define DINNER  512
#define DSTATE  64
#define NHEADS  8
#define HEADDIM 64
#define CONVDIM 640          // DINNER + 2*DSTATE
#define DPROJ   1160         // full in-proj rows (for W_in/dt indexing)
#define ZSTR    1152         // z | xBC columns actually materialized (9*128)
#define NROWS   (BATCH*SEQ)  // 32768
#define CHUNK   64
#define NCHUNK  (SEQ/CHUNK)  // 64
#define LSTR    72           // LDS row stride (shorts)

typedef short bf16x8 __attribute__((ext_vector_type(8)));
typedef short short8v __attribute__((ext_vector_type(8)));
typedef float f32x4 __attribute__((ext_vector_type(4)));

// ---- static workspace (BSS) ----
__device__ short g_xn[(size_t)NROWS * DMODEL];      // bf16 16.8 MB
__device__ short g_zxb[(size_t)NROWS * ZSTR];       // bf16 75.5 MB (z | xBC)
__device__ short g_xbc[(size_t)NROWS * CONVDIM];    // bf16 42.0 MB (conv out; x-slice overwritten by gated v)
__device__ float g_dt[(size_t)NROWS * NHEADS];      // fp32  1.0 MB (raw dt, pre-bias)
__device__ float g_rowss[(size_t)NROWS * NHEADS];   // fp32  1.0 MB (per-row per-head sum of v^2)
__device__ short g_lstate[(size_t)BATCH * NHEADS * NCHUNK * HEADDIM * DSTATE]; // bf16 33.5 MB
__device__ float g_decayC[BATCH * NHEADS * NCHUNK];
__device__ short g_Winb[(size_t)ZSTR * DMODEL];     // bf16 W_in rows 0..1151
__device__ short g_Woutb[(size_t)DMODEL * DINNER];  // bf16 W_out * gnorm_w

__device__ __forceinline__ short f2bf(float f) {
    unsigned u = __float_as_uint(f);
    u += 0x7fff + ((u >> 16) & 1);
    return (short)(u >> 16);
}
__device__ __forceinline__ float bf2f(short s) {
    return __uint_as_float(((unsigned)(unsigned short)s) << 16);
}

__device__ __forceinline__ void stage16(const void* gsrc, void* ldst) {
    __builtin_amdgcn_global_load_lds(
        (const __attribute__((address_space(1))) void*)gsrc,
        (__attribute__((address_space(3))) void*)ldst, 16, 0, 0);
}

// ---------------- weight convert: fp32 -> bf16 ----------------
__global__ __launch_bounds__(256) void convert_bf16_kernel(const float* __restrict__ src,
                                                           short* __restrict__ dst,
                                                           int n_valid, int n_total) {
    const int i = blockIdx.x * 256 + threadIdx.x;
    if (i < n_total) dst[i] = (i < n_valid) ? f2bf(src[i]) : (short)0;
}

// ---------------- W_out convert with gnorm_w folded ----------------
__global__ __launch_bounds__(256) void convert_wout_kernel(const float* __restrict__ src,
                                                           const float* __restrict__ gw,
                                                           short* __restrict__ dst) {
    const int i = blockIdx.x * 256 + threadIdx.x;
    if (i < DMODEL * DINNER) dst[i] = f2bf(src[i] * gw[i % DINNER]);
}

// ---------------- rmsnorm of x (D=256) -> bf16 xn AND exact fp32 dt (8 heads) ----------
__global__ __launch_bounds__(256) void rmsnorm_dt_kernel(const float* __restrict__ x,
                                                         const float* __restrict__ w,
                                                         const float* __restrict__ W_in,
                                                         short* __restrict__ xn,
                                                         float* __restrict__ dt) {
    const int row  = blockIdx.x * 4 + (threadIdx.x >> 6);
    const int lane = threadIdx.x & 63;
    const float4 v = *(const float4*)(x + (size_t)row * DMODEL + lane * 4);
    float ss = v.x * v.x + v.y * v.y + v.z * v.z + v.w * v.w;
#pragma unroll
    for (int off = 1; off < 64; off <<= 1) ss += __shfl_xor(ss, off);
    const float rs = rsqrtf(ss * (1.0f / DMODEL) + 1.1920929e-7f);
    const float4 wv = *(const float4*)(w + lane * 4);
    const float4 xn4 = make_float4(v.x * rs * wv.x, v.y * rs * wv.y,
                                   v.z * rs * wv.z, v.w * rs * wv.w);
    short4 o;
    o.x = f2bf(xn4.x); o.y = f2bf(xn4.y); o.z = f2bf(xn4.z); o.w = f2bf(xn4.w);
    *(short4*)(xn + (size_t)row * DMODEL + lane * 4) = o;
#pragma unroll
    for (int h = 0; h < NHEADS; ++h) {
        const float4 ww = *(const float4*)(W_in + (size_t)(DPROJ - NHEADS + h) * DMODEL + lane * 4);
        float p = xn4.x * ww.x + xn4.y * ww.y + xn4.z * ww.z + xn4.w * ww.w;
#pragma unroll
        for (int off = 1; off < 64; off <<= 1) p += __shfl_xor(p, off);
        if (lane == 0) dt[(size_t)row * NHEADS + h] = p;
    }
}

// ---------------- bf16 MFMA GEMM: C[M][N] = A[M][K] * B[N][K]^T ----------
// BK=64, XCD-chunked grid swizzle, B-row permute -> packed stores, chunk-XOR
// LDS swizzle both-sides. RES path (GEMM2): per-row rs = rsqrt(sum8(RS)/512+eps)
// applied in epilogue before residual (fused gated-RMSNorm scale).
template <bool RES, typename OUT>
__global__ __launch_bounds__(256) void gemm_bf16_nt(const short* __restrict__ A,
                                                    const short* __restrict__ B,
                                                    const float* __restrict__ R,
                                                    const float* __restrict__ RS,
                                                    OUT* __restrict__ C,
                                                    int NX, int M, int N, int K, int LDA) {
    const int L   = blockIdx.x;
    const int xcd = L & 7;
    const int r   = L >> 3;
    const int mstrips_per_xcd = (M / 128) >> 3;
    const int mblk = xcd * mstrips_per_xcd + r / NX;
    const int nblk = r % NX;
    const int m0 = mblk * 128, n0 = nblk * 128;

    __shared__ __align__(16) short Asl[128 * 64];   // 16 KB
    __shared__ __align__(16) short Bsl[128 * 64];   // 16 KB
    const int tid  = threadIdx.x;
    const int lane = tid & 63;
    const int wid  = tid >> 6;
    const int wrow = (wid >> 1) * 64, wcol = (wid & 1) * 64;

    f32x4 acc[4][4];
#pragma unroll
    for (int m = 0; m < 4; ++m)
#pragma unroll
        for (int n = 0; n < 4; ++n) acc[m][n] = (f32x4)0.f;

    const int wbase = (tid & 0xC0) * 8;             // wave-uniform LDS elem base

    for (int k0 = 0; k0 < K; k0 += 64) {
#pragma unroll
        for (int rr = 0; rr < 4; ++rr) {
            const int idx = rr * 256 + tid;         // 0..1023
            const int row = idx >> 3;               // LDS slot row 0..127
            const int cs  = idx & 7;                // chunk slot 0..7
            const int ko  = (cs ^ (row & 7)) * 8;   // pre-swizzled source chunk
            const int r6  = row & 63;
            const int brow = (row & 64) + (((r6 & 15) << 2) | (r6 >> 4));  // store permute
            stage16(A + (size_t)(m0 + row) * LDA + k0 + ko, Asl + rr * 2048 + wbase);
            stage16(B + (size_t)(n0 + brow) * K + k0 + ko, Bsl + rr * 2048 + wbase);
        }
        __syncthreads();
#pragma unroll
        for (int ks = 0; ks < 2; ++ks) {
            bf16x8 af[4], bfr[4];
#pragma unroll
            for (int m = 0; m < 4; ++m) {
                const int arow = wrow + m * 16 + (lane & 15);
                const int ch = (ks * 4 + (lane >> 4)) ^ (arow & 7);
                af[m] = *(const bf16x8*)(Asl + arow * 64 + ch * 8);
            }
#pragma unroll
            for (int n = 0; n < 4; ++n) {
                const int brw = wcol + n * 16 + (lane & 15);
                const int ch = (ks * 4 + (lane >> 4)) ^ (brw & 7);
                bfr[n] = *(const bf16x8*)(Bsl + brw * 64 + ch * 8);
            }
#pragma unroll
            for (int m = 0; m < 4; ++m)
#pragma unroll
                for (int n = 0; n < 4; ++n)
                    acc[m][n] = __builtin_amdgcn_mfma_f32_16x16x32_bf16(af[m], bfr[n], acc[m][n], 0, 0, 0);
        }
        __syncthreads();
    }

    const int r0 = (lane >> 4) * 4;
    const int gcol = n0 + wcol + (lane & 15) * 4;
#pragma unroll
    for (int m = 0; m < 4; ++m) {
        const int grow = m0 + wrow + m * 16 + r0;
        if (gcol < N) {
#pragma unroll
            for (int reg = 0; reg < 4; ++reg) {
                if constexpr (sizeof(OUT) == 2) {
                    short4 o;
                    o.x = f2bf(acc[m][0][reg]); o.y = f2bf(acc[m][1][reg]);
                    o.z = f2bf(acc[m][2][reg]); o.w = f2bf(acc[m][3][reg]);
                    *(short4*)(C + (size_t)(grow + reg) * N + gcol) = o;
                } else {
                    f32x4 v;
                    v[0] = acc[m][0][reg]; v[1] = acc[m][1][reg];
                    v[2] = acc[m][2][reg]; v[3] = acc[m][3][reg];
                    if (RES) {
                        const float* rp = RS + (size_t)(grow + reg) * NHEADS;
                        const f32x4 s0 = *(const f32x4*)rp;
                        const f32x4 s1 = *(const f32x4*)(rp + 4);
                        const float sum = s0[0] + s0[1] + s0[2] + s0[3] +
                                          s1[0] + s1[1] + s1[2] + s1[3];
                        const float rsn = rsqrtf(sum * (1.0f / DINNER) + 1e-5f);
                        v *= rsn;
                        v += *(const f32x4*)(R + (size_t)(grow + reg) * N + gcol);
                    }
                    *(f32x4*)(C + (size_t)(grow + reg) * N + gcol) = v;
                }
            }
        }
    }
}

// ---- depthwise causal conv(4) + bias + SiLU: sliding window, 8 rows x 8 ch per thread ----
__global__ __launch_bounds__(256) void conv_silu_kernel(const short* __restrict__ zxb,
                                                        const float* __restrict__ cw,
                                                        const float* __restrict__ cb,
                                                        short* __restrict__ xbc) {
    const int idx = blockIdx.x * 256 + threadIdx.x;   // over (NROWS/8)*80
    const int c8  = (idx % 80) * 8;
    const int bl0 = (idx / 80) * 8;                   // first of 8 rows
    const int l0  = bl0 & (SEQ - 1);
    const short* src = zxb + (size_t)bl0 * ZSTR + DINNER + c8;

    float4 w4[8];
    float bias[8];
#pragma unroll
    for (int j = 0; j < 8; ++j) w4[j] = *(const float4*)(cw + (c8 + j) * 4);
    {
        const float4 b0 = *(const float4*)(cb + c8);
        const float4 b1 = *(const float4*)(cb + c8 + 4);
        bias[0] = b0.x; bias[1] = b0.y; bias[2] = b0.z; bias[3] = b0.w;
        bias[4] = b1.x; bias[5] = b1.y; bias[6] = b1.z; bias[7] = b1.w;
    }

    bf16x8 rowv[11];                                  // rows l0-3 .. l0+7
#pragma unroll
    for (int m = 0; m < 11; ++m) {
        if (l0 + m - 3 >= 0)
            rowv[m] = *(const bf16x8*)(src + (ptrdiff_t)(m - 3) * ZSTR);
        else
            rowv[m] = (bf16x8)0;
    }

#pragma unroll
    for (int r = 0; r < 8; ++r) {
        float acc[8];
#pragma unroll
        for (int j = 0; j < 8; ++j) acc[j] = bias[j];
#pragma unroll
        for (int k = 0; k < 4; ++k) {
            const bf16x8 tap = rowv[r + k];
#pragma unroll
            for (int j = 0; j < 8; ++j)
                acc[j] = fmaf(bf2f(tap[j]), ((const float*)&w4[j])[k], acc[j]);
        }
        short8v o;
#pragma unroll
        for (int j = 0; j < 8; ++j) {
            const float s = acc[j];
            o[j] = f2bf(s / (1.f + __expf(-s)));
        }
        *(short8v*)(xbc + (size_t)(bl0 + r) * CONVDIM + c8) = o;
    }
}

// ---------------- scan pass 1 (MFMA): L[p][n] = sum_t X[t][p] * (w_t * B[t][n]) ----------
// XT AND BT slot-permuted (channel 4q+i -> slot i*16+q): staging writes hit
// 16-strided rows (~2-way banks, was 16-way). lstate store compensates with
// true_p = 16*hi + 4*reg + wid (bijective); global layout stays [p][n].
__global__ __launch_bounds__(256) void chunk_state_mfma(const float* __restrict__ dt,
                                                        const short* __restrict__ xbc,
                                                        const float* __restrict__ dt_bias,
                                                        const float* __restrict__ A_log,
                                                        short* __restrict__ lstate,
                                                        float* __restrict__ decayC) {
    const int bhc = blockIdx.x;
    const int c = bhc & (NCHUNK - 1), bh = bhc >> 6, h = bh & (NHEADS - 1), b = bh >> 3;
    const int tid = threadIdx.x, lane = tid & 63, wid = tid >> 6;
    __shared__ short XT[64 * LSTR];   // X^T, slot-permuted
    __shared__ short BT[64 * LSTR];   // (w*B)^T, slot-permuted
    __shared__ float wsh[CHUNK];
    const size_t row0 = (size_t)b * SEQ + (size_t)c * CHUNK;

    const float aneg  = -__expf(A_log[h]);
    const float dbias = dt_bias[h];
    if (tid < 64) {
        const float draw = dt[(row0 + tid) * NHEADS + h] + dbias;
        const float dtv  = (draw > 20.f) ? draw : log1pf(__expf(draw));
        float cum = aneg * dtv;
#pragma unroll
        for (int off = 1; off < 64; off <<= 1) {
            const float nv = __shfl_up(cum, off);
            if (lane >= off) cum += nv;
        }
        const float total = __shfl(cum, 63);
        wsh[tid] = __expf(total - cum) * dtv;
        if (tid == 63) decayC[bhc] = __expf(cum);
    }
    __syncthreads();

#pragma unroll
    for (int r = 0; r < 4; ++r) {
        const int idx  = tid + r * 256;
        const int trow = idx >> 4;
        const int q    = idx & 15;                 // channel group: channels 4q..4q+3
        const int c4   = q * 4;
        const short* rp = xbc + (row0 + trow) * CONVDIM;
        const short4 xv = *(const short4*)(rp + h * 64 + c4);
        const short4 bv = *(const short4*)(rp + DINNER + c4);
        const float w = wsh[trow];
        // channel c4+i -> slot (i*16 + q) for BOTH operands
        XT[(0 * 16 + q) * LSTR + trow] = xv.x;
        XT[(1 * 16 + q) * LSTR + trow] = xv.y;
        XT[(2 * 16 + q) * LSTR + trow] = xv.z;
        XT[(3 * 16 + q) * LSTR + trow] = xv.w;
        BT[(0 * 16 + q) * LSTR + trow] = f2bf(bf2f(bv.x) * w);
        BT[(1 * 16 + q) * LSTR + trow] = f2bf(bf2f(bv.y) * w);
        BT[(2 * 16 + q) * LSTR + trow] = f2bf(bf2f(bv.z) * w);
        BT[(3 * 16 + q) * LSTR + trow] = f2bf(bf2f(bv.w) * w);
    }
    __syncthreads();

    f32x4 acc[4];
#pragma unroll
    for (int n = 0; n < 4; ++n) acc[n] = (f32x4)0.f;
#pragma unroll
    for (int ks = 0; ks < 2; ++ks) {
        const bf16x8 af = *(const bf16x8*)(XT + (wid * 16 + (lane & 15)) * LSTR + ks * 32 + (lane >> 4) * 8);
#pragma unroll
        for (int n = 0; n < 4; ++n) {
            const bf16x8 bfv = *(const bf16x8*)(BT + (n * 16 + (lane & 15)) * LSTR + ks * 32 + (lane >> 4) * 8);
            acc[n] = __builtin_amdgcn_mfma_f32_16x16x32_bf16(af, bfv, acc[n], 0, 0, 0);
        }
    }
    // acc row slot = wid*16 + 4*hi + reg represents true p = 16*hi + 4*reg + wid
    short* lp = lstate + ((size_t)bhc << 12);
    const int hi = lane >> 4;
    const int ncol = (lane & 15) * 4;
#pragma unroll
    for (int reg = 0; reg < 4; ++reg) {
        const int p = 16 * hi + 4 * reg + wid;
        short4 o;
        o.x = f2bf(acc[0][reg]); o.y = f2bf(acc[1][reg]);
        o.z = f2bf(acc[2][reg]); o.w = f2bf(acc[3][reg]);
        *(short4*)(lp + p * 64 + ncol) = o;
    }
}

// ---------------- scan pass 2: inter-chunk recurrence, short4-wide ----------
__global__ __launch_bounds__(256) void state_prefix_kernel(short* __restrict__ lstate,
                                                           const float* __restrict__ decayC) {
    const int idx = blockIdx.x * 256 + threadIdx.x;   // over BATCH*NHEADS*1024
    const int bh  = idx >> 10;
    const int pn4 = (idx & 1023) * 4;
    float S0 = 0.f, S1 = 0.f, S2 = 0.f, S3 = 0.f;
    for (int c = 0; c < NCHUNK; ++c) {
        short4* ptr = (short4*)(lstate + (((size_t)bh * NCHUNK + c) << 12) + pn4);
        const short4 l4 = *ptr;
        short4 o;
        o.x = f2bf(S0); o.y = f2bf(S1); o.z = f2bf(S2); o.w = f2bf(S3);
        *ptr = o;
        const float d = decayC[bh * NCHUNK + c];
        S0 = fmaf(S0, d, bf2f(l4.x));
        S1 = fmaf(S1, d, bf2f(l4.y));
        S2 = fmaf(S2, d, bf2f(l4.z));
        S3 = fmaf(S3, d, bf2f(l4.w));
    }
}

// ---- scan pass 3 (MFMA): y = mask(C@B^T)@X + exp(cum)*(C@SP^T) + Dp*X, fused gating.
// Ms OVERLAYS Bs (Bs dead after G phase) -> LDS 37.4 KB -> 4 blocks/CU. ----
__global__ __launch_bounds__(256) void chunk_scan_mfma(const float* __restrict__ dt,
                                                       short* __restrict__ xbc,
                                                       const short* __restrict__ zxb,
                                                       float* __restrict__ rowss,
                                                       const float* __restrict__ dt_bias,
                                                       const float* __restrict__ A_log,
                                                       const float* __restrict__ Dp,
                                                       const short* __restrict__ lstate) {
    const int bhc = blockIdx.x;
    const int c = bhc & (NCHUNK - 1), bh = bhc >> 6, h = bh & (NHEADS - 1), b = bh >> 3;
    const int tid = threadIdx.x, lane = tid & 63, wid = tid >> 6;
    __shared__ short BsMs[64 * LSTR]; // B rows [t][n]; later masked scores [s][t]
    __shared__ short Cs[64 * LSTR];   // C rows [s][n]
    __shared__ short XT[64 * LSTR];   // X^T, slot-permuted
    __shared__ short SP[64 * LSTR];   // prefix state, slot-permuted
    __shared__ float cums[CHUNK];
    __shared__ float dtss[CHUNK];
    short* Bs = BsMs;
    short* Ms = BsMs;
    const size_t row0 = (size_t)b * SEQ + (size_t)c * CHUNK;

#pragma unroll
    for (int r = 0; r < 4; ++r) {
        const int idx  = tid + r * 256;
        const int trow = idx >> 4;
        const int q    = idx & 15;
        const int c4   = q * 4;
        const short* rp = xbc + (row0 + trow) * CONVDIM;
        const short4 xv = *(const short4*)(rp + h * 64 + c4);
        *(short4*)(Bs + trow * LSTR + c4) = *(const short4*)(rp + DINNER + c4);
        *(short4*)(Cs + trow * LSTR + c4) = *(const short4*)(rp + DINNER + DSTATE + c4);
        // p-row c4+i -> slot (i*16 + q)
        XT[(0 * 16 + q) * LSTR + trow] = xv.x;
        XT[(1 * 16 + q) * LSTR + trow] = xv.y;
        XT[(2 * 16 + q) * LSTR + trow] = xv.z;
        XT[(3 * 16 + q) * LSTR + trow] = xv.w;
    }
#pragma unroll
    for (int r = 0; r < 4; ++r) {
        const int idx = tid + r * 256;
        const int p = idx >> 4, n4 = (idx & 15) * 4;
        const int pslot = ((p & 3) << 4) | (p >> 2);
        *(short4*)(SP + pslot * LSTR + n4) =
            *(const short4*)(lstate + ((size_t)bhc << 12) + p * 64 + n4);
    }
    const float aneg  = -__expf(A_log[h]);
    const float dbias = dt_bias[h];
    if (tid < 64) {
        const float draw = dt[(row0 + tid) * NHEADS + h] + dbias;
        const float dtv  = (draw > 20.f) ? draw : log1pf(__expf(draw));
        float cum = aneg * dtv;
#pragma unroll
        for (int off = 1; off < 64; off <<= 1) {
            const float nv = __shfl_up(cum, off);
            if (lane >= off) cum += nv;
        }
        cums[tid] = cum;
        dtss[tid] = dtv;
    }
    __syncthreads();

    // G = C @ B^T (over n)
    f32x4 accG[4];
#pragma unroll
    for (int tf = 0; tf < 4; ++tf) accG[tf] = (f32x4)0.f;
#pragma unroll
    for (int ks = 0; ks < 2; ++ks) {
        const bf16x8 af = *(const bf16x8*)(Cs + (wid * 16 + (lane & 15)) * LSTR + ks * 32 + (lane >> 4) * 8);
#pragma unroll
        for (int tf = 0; tf < 4; ++tf) {
            const bf16x8 bfv = *(const bf16x8*)(Bs + (tf * 16 + (lane & 15)) * LSTR + ks * 32 + (lane >> 4) * 8);
            accG[tf] = __builtin_amdgcn_mfma_f32_16x16x32_bf16(af, bfv, accG[tf], 0, 0, 0);
        }
    }
    __syncthreads();   // all waves done reading Bs before Ms overlays it

    // causal mask + decay scale -> Ms (bf16), overlaid on Bs
    const int srow0 = wid * 16 + (lane >> 4) * 4;
#pragma unroll
    for (int tf = 0; tf < 4; ++tf) {
        const int t = tf * 16 + (lane & 15);
        const float ct  = cums[t];
        const float dtt = dtss[t];
#pragma unroll
        for (int reg = 0; reg < 4; ++reg) {
            const int s = srow0 + reg;
            const float m = (t <= s) ? accG[tf][reg] * __expf(cums[s] - ct) * dtt : 0.f;
            Ms[s * LSTR + t] = f2bf(m);
        }
    }
    __syncthreads();

    // Y1 = M @ X ; Y2 = C @ SP^T  (B-operands slot-permuted: pos j of frag pf = p-row 4j+pf)
    f32x4 acc1[4], acc2[4];
#pragma unroll
    for (int pf = 0; pf < 4; ++pf) { acc1[pf] = (f32x4)0.f; acc2[pf] = (f32x4)0.f; }
#pragma unroll
    for (int ks = 0; ks < 2; ++ks) {
        const bf16x8 am = *(const bf16x8*)(Ms + (wid * 16 + (lane & 15)) * LSTR + ks * 32 + (lane >> 4) * 8);
        const bf16x8 ac = *(const bf16x8*)(Cs + (wid * 16 + (lane & 15)) * LSTR + ks * 32 + (lane >> 4) * 8);
#pragma unroll
        for (int pf = 0; pf < 4; ++pf) {
            const bf16x8 bx = *(const bf16x8*)(XT + (pf * 16 + (lane & 15)) * LSTR + ks * 32 + (lane >> 4) * 8);
            const bf16x8 bs = *(const bf16x8*)(SP + (pf * 16 + (lane & 15)) * LSTR + ks * 32 + (lane >> 4) * 8);
            acc1[pf] = __builtin_amdgcn_mfma_f32_16x16x32_bf16(am, bx, acc1[pf], 0, 0, 0);
            acc2[pf] = __builtin_amdgcn_mfma_f32_16x16x32_bf16(ac, bs, acc2[pf], 0, 0, 0);
        }
    }
    const float dpv = Dp[h];
    float es[4];
#pragma unroll
    for (int reg = 0; reg < 4; ++reg) es[reg] = __expf(cums[srow0 + reg]);
    const int j = lane & 15;
#pragma unroll
    for (int reg = 0; reg < 4; ++reg) {
        const int s = srow0 + reg;
        const short4 z4 = *(const short4*)(zxb + (row0 + s) * ZSTR + h * 64 + j * 4);
        short4 o;
        float ssq = 0.f;
#pragma unroll
        for (int pf = 0; pf < 4; ++pf) {
            const float xv = bf2f(XT[(pf * 16 + j) * LSTR + s]);
            const float yv = acc1[pf][reg] + es[reg] * acc2[pf][reg] + dpv * xv;
            const float zf = bf2f(((const short*)&z4)[pf]);
            const float v  = yv * zf / (1.f + __expf(-zf));
            ((short*)&o)[pf] = f2bf(v);
            ssq = fmaf(v, v, ssq);
        }
        *(short4*)(xbc + (row0 + s) * CONVDIM + h * 64 + j * 4) = o;
        ssq += __shfl_xor(ssq, 1);
        ssq += __shfl_xor(ssq, 2);
        ssq += __shfl_xor(ssq, 4);
        ssq += __shfl_xor(ssq, 8);
        if (j == 0) rowss[(row0 + s) * NHEADS + h] = ssq;
    }
}

// ---------------- launch ----------------
extern "C" void kernel_launch(void* const* d_in, const int* in_sizes, int n_in,
                              void* d_out, int out_size, void* d_ws, size_t ws_size,
                              hipStream_t stream) {
    (void)in_sizes; (void)n_in; (void)out_size; (void)d_ws; (void)ws_size;
    const float* x      = (const float*)d_in[0];
    const float* W_in   = (const float*)d_in[1];
    const float* conv_w = (const float*)d_in[2];
    const float* conv_b = (const float*)d_in[3];
    const float* dt_b   = (const float*)d_in[4];
    const float* A_log  = (const float*)d_in[5];
    const float* Dp     = (const float*)d_in[6];
    const float* g_w    = (const float*)d_in[7];
    const float* n_w    = (const float*)d_in[8];
    const float* W_out  = (const float*)d_in[9];
    float* out = (float*)d_out;

    short *xn, *zxb, *xbc, *winb, *woutb, *lst;
    float *dtv, *dcy, *rss;
    hipGetSymbolAddress((void**)&xn,    HIP_SYMBOL(g_xn));
    hipGetSymbolAddress((void**)&zxb,   HIP_SYMBOL(g_zxb));
    hipGetSymbolAddress((void**)&xbc,   HIP_SYMBOL(g_xbc));
    hipGetSymbolAddress((void**)&dtv,   HIP_SYMBOL(g_dt));
    hipGetSymbolAddress((void**)&rss,   HIP_SYMBOL(g_rowss));
    hipGetSymbolAddress((void**)&lst,   HIP_SYMBOL(g_lstate));
    hipGetSymbolAddress((void**)&dcy,   HIP_SYMBOL(g_decayC));
    hipGetSymbolAddress((void**)&winb,  HIP_SYMBOL(g_Winb));
    hipGetSymbolAddress((void**)&woutb, HIP_SYMBOL(g_Woutb));

    convert_bf16_kernel<<<(ZSTR * DMODEL) / 256, 256, 0, stream>>>(
        W_in, winb, ZSTR * DMODEL, ZSTR * DMODEL);
    convert_wout_kernel<<<(DMODEL * DINNER) / 256, 256, 0, stream>>>(W_out, g_w, woutb);

    rmsnorm_dt_kernel<<<NROWS / 4, 256, 0, stream>>>(x, n_w, W_in, xn, dtv);

    gemm_bf16_nt<false, short><<<(ZSTR / 128) * (NROWS / 128), 256, 0, stream>>>(
        xn, winb, nullptr, nullptr, zxb, ZSTR / 128, NROWS, ZSTR, DMODEL, DMODEL);

    conv_silu_kernel<<<(NROWS / 8 * 80) / 256, 256, 0, stream>>>(zxb, conv_w, conv_b, xbc);

    chunk_state_mfma<<<BATCH * NHEADS * NCHUNK, 256, 0, stream>>>(dtv, xbc, dt_b, A_log, lst, dcy);
    state_prefix_kernel<<<(BATCH * NHEADS * HEADDIM * DSTATE) / (4 * 256), 256, 0, stream>>>(lst, dcy);
    chunk_scan_mfma<<<BATCH * NHEADS * NCHUNK, 256, 0, stream>>>(
        dtv, xbc, zxb, rss, dt_b, A_log, Dp, lst);

    gemm_bf16_nt<true, float><<<(DMODEL / 128) * (NROWS / 128), 256, 0, stream>>>(
        xbc, woutb, x, rss, out, DMODEL / 128, NROWS, DMODEL, DINNER, CONVDIM);
}

// Round 13
// 173.204 us; speedup vs baseline: 1.3583x; 1.0095x over previous
//
#include <hip/hip_runtime.h>
#include <math.h>

#define BATCH   8
#define SEQ     4096
#define DMODEL  256
#define DINNER  512
#define DSTATE  64
#define NHEADS  8
#define HEADDIM 64
#define CONVDIM 640          // DINNER + 2*DSTATE
#define DPROJ   1160         // full in-proj rows (for W_in/dt indexing)
#define ZSTR    1152         // z | xBC columns actually materialized (9*128)
#define NROWS   (BATCH*SEQ)  // 32768
#define CHUNK   64
#define NCHUNK  (SEQ/CHUNK)  // 64
#define LSTR    72           // LDS row stride for chunk_state (shorts)

typedef short bf16x8 __attribute__((ext_vector_type(8)));
typedef short short8v __attribute__((ext_vector_type(8)));
typedef float f32x4 __attribute__((ext_vector_type(4)));

// ---- static workspace (BSS) ----
__device__ short g_xn[(size_t)NROWS * DMODEL];      // bf16 16.8 MB
__device__ short g_zxb[(size_t)NROWS * ZSTR];       // bf16 75.5 MB (z | xBC)
__device__ short g_xbc[(size_t)NROWS * CONVDIM];    // bf16 42.0 MB (conv out; x-slice overwritten by gated v)
__device__ float g_dt[(size_t)NROWS * NHEADS];      // fp32  1.0 MB (raw dt, pre-bias)
__device__ float g_rowss[(size_t)NROWS * NHEADS];   // fp32  1.0 MB (per-row per-head sum of v^2)
__device__ short g_lstate[(size_t)BATCH * NHEADS * NCHUNK * HEADDIM * DSTATE]; // bf16 33.5 MB
__device__ float g_decayC[BATCH * NHEADS * NCHUNK];
__device__ short g_Winb[(size_t)ZSTR * DMODEL];     // bf16 W_in rows 0..1151
__device__ short g_Woutb[(size_t)DMODEL * DINNER];  // bf16 W_out * gnorm_w

__device__ __forceinline__ short f2bf(float f) {
    unsigned u = __float_as_uint(f);
    u += 0x7fff + ((u >> 16) & 1);
    return (short)(u >> 16);
}
__device__ __forceinline__ float bf2f(short s) {
    return __uint_as_float(((unsigned)(unsigned short)s) << 16);
}

__device__ __forceinline__ void stage16(const void* gsrc, void* ldst) {
    __builtin_amdgcn_global_load_lds(
        (const __attribute__((address_space(1))) void*)gsrc,
        (__attribute__((address_space(3))) void*)ldst, 16, 0, 0);
}

// element offset in a [64][64] bf16 tile with XOR chunk swizzle
__device__ __forceinline__ int swz(int row, int col) {
    return row * 64 + ((((col >> 3) ^ row) & 7) << 3) + (col & 7);
}

// ---------------- weight convert: fp32 -> bf16 ----------------
__global__ __launch_bounds__(256) void convert_bf16_kernel(const float* __restrict__ src,
                                                           short* __restrict__ dst,
                                                           int n_valid, int n_total) {
    const int i = blockIdx.x * 256 + threadIdx.x;
    if (i < n_total) dst[i] = (i < n_valid) ? f2bf(src[i]) : (short)0;
}

// ---------------- W_out convert with gnorm_w folded ----------------
__global__ __launch_bounds__(256) void convert_wout_kernel(const float* __restrict__ src,
                                                           const float* __restrict__ gw,
                                                           short* __restrict__ dst) {
    const int i = blockIdx.x * 256 + threadIdx.x;
    if (i < DMODEL * DINNER) dst[i] = f2bf(src[i] * gw[i % DINNER]);
}

// ---------------- rmsnorm of x (D=256) -> bf16 xn AND exact fp32 dt (8 heads) ----------
__global__ __launch_bounds__(256) void rmsnorm_dt_kernel(const float* __restrict__ x,
                                                         const float* __restrict__ w,
                                                         const float* __restrict__ W_in,
                                                         short* __restrict__ xn,
                                                         float* __restrict__ dt) {
    const int row  = blockIdx.x * 4 + (threadIdx.x >> 6);
    const int lane = threadIdx.x & 63;
    const float4 v = *(const float4*)(x + (size_t)row * DMODEL + lane * 4);
    float ss = v.x * v.x + v.y * v.y + v.z * v.z + v.w * v.w;
#pragma unroll
    for (int off = 1; off < 64; off <<= 1) ss += __shfl_xor(ss, off);
    const float rs = rsqrtf(ss * (1.0f / DMODEL) + 1.1920929e-7f);
    const float4 wv = *(const float4*)(w + lane * 4);
    const float4 xn4 = make_float4(v.x * rs * wv.x, v.y * rs * wv.y,
                                   v.z * rs * wv.z, v.w * rs * wv.w);
    short4 o;
    o.x = f2bf(xn4.x); o.y = f2bf(xn4.y); o.z = f2bf(xn4.z); o.w = f2bf(xn4.w);
    *(short4*)(xn + (size_t)row * DMODEL + lane * 4) = o;
#pragma unroll
    for (int h = 0; h < NHEADS; ++h) {
        const float4 ww = *(const float4*)(W_in + (size_t)(DPROJ - NHEADS + h) * DMODEL + lane * 4);
        float p = xn4.x * ww.x + xn4.y * ww.y + xn4.z * ww.z + xn4.w * ww.w;
#pragma unroll
        for (int off = 1; off < 64; off <<= 1) p += __shfl_xor(p, off);
        if (lane == 0) dt[(size_t)row * NHEADS + h] = p;
    }
}

// ---------------- bf16 MFMA GEMM: C[M][N] = A[M][K] * B[N][K]^T ----------
template <bool RES, typename OUT>
__global__ __launch_bounds__(256) void gemm_bf16_nt(const short* __restrict__ A,
                                                    const short* __restrict__ B,
                                                    const float* __restrict__ R,
                                                    const float* __restrict__ RS,
                                                    OUT* __restrict__ C,
                                                    int NX, int M, int N, int K, int LDA) {
    const int L   = blockIdx.x;
    const int xcd = L & 7;
    const int r   = L >> 3;
    const int mstrips_per_xcd = (M / 128) >> 3;
    const int mblk = xcd * mstrips_per_xcd + r / NX;
    const int nblk = r % NX;
    const int m0 = mblk * 128, n0 = nblk * 128;

    __shared__ __align__(16) short Asl[128 * 64];   // 16 KB
    __shared__ __align__(16) short Bsl[128 * 64];   // 16 KB
    const int tid  = threadIdx.x;
    const int lane = tid & 63;
    const int wid  = tid >> 6;
    const int wrow = (wid >> 1) * 64, wcol = (wid & 1) * 64;

    f32x4 acc[4][4];
#pragma unroll
    for (int m = 0; m < 4; ++m)
#pragma unroll
        for (int n = 0; n < 4; ++n) acc[m][n] = (f32x4)0.f;

    const int wbase = (tid & 0xC0) * 8;

    for (int k0 = 0; k0 < K; k0 += 64) {
#pragma unroll
        for (int rr = 0; rr < 4; ++rr) {
            const int idx = rr * 256 + tid;
            const int row = idx >> 3;
            const int cs  = idx & 7;
            const int ko  = (cs ^ (row & 7)) * 8;
            const int r6  = row & 63;
            const int brow = (row & 64) + (((r6 & 15) << 2) | (r6 >> 4));
            stage16(A + (size_t)(m0 + row) * LDA + k0 + ko, Asl + rr * 2048 + wbase);
            stage16(B + (size_t)(n0 + brow) * K + k0 + ko, Bsl + rr * 2048 + wbase);
        }
        __syncthreads();
#pragma unroll
        for (int ks = 0; ks < 2; ++ks) {
            bf16x8 af[4], bfr[4];
#pragma unroll
            for (int m = 0; m < 4; ++m) {
                const int arow = wrow + m * 16 + (lane & 15);
                const int ch = (ks * 4 + (lane >> 4)) ^ (arow & 7);
                af[m] = *(const bf16x8*)(Asl + arow * 64 + ch * 8);
            }
#pragma unroll
            for (int n = 0; n < 4; ++n) {
                const int brw = wcol + n * 16 + (lane & 15);
                const int ch = (ks * 4 + (lane >> 4)) ^ (brw & 7);
                bfr[n] = *(const bf16x8*)(Bsl + brw * 64 + ch * 8);
            }
#pragma unroll
            for (int m = 0; m < 4; ++m)
#pragma unroll
                for (int n = 0; n < 4; ++n)
                    acc[m][n] = __builtin_amdgcn_mfma_f32_16x16x32_bf16(af[m], bfr[n], acc[m][n], 0, 0, 0);
        }
        __syncthreads();
    }

    const int r0 = (lane >> 4) * 4;
    const int gcol = n0 + wcol + (lane & 15) * 4;
#pragma unroll
    for (int m = 0; m < 4; ++m) {
        const int grow = m0 + wrow + m * 16 + r0;
        if (gcol < N) {
#pragma unroll
            for (int reg = 0; reg < 4; ++reg) {
                if constexpr (sizeof(OUT) == 2) {
                    short4 o;
                    o.x = f2bf(acc[m][0][reg]); o.y = f2bf(acc[m][1][reg]);
                    o.z = f2bf(acc[m][2][reg]); o.w = f2bf(acc[m][3][reg]);
                    *(short4*)(C + (size_t)(grow + reg) * N + gcol) = o;
                } else {
                    f32x4 v;
                    v[0] = acc[m][0][reg]; v[1] = acc[m][1][reg];
                    v[2] = acc[m][2][reg]; v[3] = acc[m][3][reg];
                    if (RES) {
                        const float* rp = RS + (size_t)(grow + reg) * NHEADS;
                        const f32x4 s0 = *(const f32x4*)rp;
                        const f32x4 s1 = *(const f32x4*)(rp + 4);
                        const float sum = s0[0] + s0[1] + s0[2] + s0[3] +
                                          s1[0] + s1[1] + s1[2] + s1[3];
                        const float rsn = rsqrtf(sum * (1.0f / DINNER) + 1e-5f);
                        v *= rsn;
                        v += *(const f32x4*)(R + (size_t)(grow + reg) * N + gcol);
                    }
                    *(f32x4*)(C + (size_t)(grow + reg) * N + gcol) = v;
                }
            }
        }
    }
}

// ---- depthwise causal conv(4) + bias + SiLU: sliding window, 8 rows x 8 ch per thread ----
__global__ __launch_bounds__(256) void conv_silu_kernel(const short* __restrict__ zxb,
                                                        const float* __restrict__ cw,
                                                        const float* __restrict__ cb,
                                                        short* __restrict__ xbc) {
    const int idx = blockIdx.x * 256 + threadIdx.x;   // over (NROWS/8)*80
    const int c8  = (idx % 80) * 8;
    const int bl0 = (idx / 80) * 8;                   // first of 8 rows
    const int l0  = bl0 & (SEQ - 1);
    const short* src = zxb + (size_t)bl0 * ZSTR + DINNER + c8;

    float4 w4[8];
    float bias[8];
#pragma unroll
    for (int j = 0; j < 8; ++j) w4[j] = *(const float4*)(cw + (c8 + j) * 4);
    {
        const float4 b0 = *(const float4*)(cb + c8);
        const float4 b1 = *(const float4*)(cb + c8 + 4);
        bias[0] = b0.x; bias[1] = b0.y; bias[2] = b0.z; bias[3] = b0.w;
        bias[4] = b1.x; bias[5] = b1.y; bias[6] = b1.z; bias[7] = b1.w;
    }

    bf16x8 rowv[11];                                  // rows l0-3 .. l0+7
#pragma unroll
    for (int m = 0; m < 11; ++m) {
        if (l0 + m - 3 >= 0)
            rowv[m] = *(const bf16x8*)(src + (ptrdiff_t)(m - 3) * ZSTR);
        else
            rowv[m] = (bf16x8)0;
    }

#pragma unroll
    for (int r = 0; r < 8; ++r) {
        float acc[8];
#pragma unroll
        for (int j = 0; j < 8; ++j) acc[j] = bias[j];
#pragma unroll
        for (int k = 0; k < 4; ++k) {
            const bf16x8 tap = rowv[r + k];
#pragma unroll
            for (int j = 0; j < 8; ++j)
                acc[j] = fmaf(bf2f(tap[j]), ((const float*)&w4[j])[k], acc[j]);
        }
        short8v o;
#pragma unroll
        for (int j = 0; j < 8; ++j) {
            const float s = acc[j];
            o[j] = f2bf(s / (1.f + __expf(-s)));
        }
        *(short8v*)(xbc + (size_t)(bl0 + r) * CONVDIM + c8) = o;
    }
}

// ---------------- scan pass 1 (MFMA): L[p][n] = sum_t X[t][p] * (w_t * B[t][n]) ----------
__global__ __launch_bounds__(256) void chunk_state_mfma(const float* __restrict__ dt,
                                                        const short* __restrict__ xbc,
                                                        const float* __restrict__ dt_bias,
                                                        const float* __restrict__ A_log,
                                                        short* __restrict__ lstate,
                                                        float* __restrict__ decayC) {
    const int bhc = blockIdx.x;
    const int c = bhc & (NCHUNK - 1), bh = bhc >> 6, h = bh & (NHEADS - 1), b = bh >> 3;
    const int tid = threadIdx.x, lane = tid & 63, wid = tid >> 6;
    __shared__ short XT[64 * LSTR];   // X^T, slot-permuted
    __shared__ short BT[64 * LSTR];   // (w*B)^T, slot-permuted
    __shared__ float wsh[CHUNK];
    const size_t row0 = (size_t)b * SEQ + (size_t)c * CHUNK;

    const float aneg  = -__expf(A_log[h]);
    const float dbias = dt_bias[h];
    if (tid < 64) {
        const float draw = dt[(row0 + tid) * NHEADS + h] + dbias;
        const float dtv  = (draw > 20.f) ? draw : log1pf(__expf(draw));
        float cum = aneg * dtv;
#pragma unroll
        for (int off = 1; off < 64; off <<= 1) {
            const float nv = __shfl_up(cum, off);
            if (lane >= off) cum += nv;
        }
        const float total = __shfl(cum, 63);
        wsh[tid] = __expf(total - cum) * dtv;
        if (tid == 63) decayC[bhc] = __expf(cum);
    }
    __syncthreads();

#pragma unroll
    for (int r = 0; r < 4; ++r) {
        const int idx  = tid + r * 256;
        const int trow = idx >> 4;
        const int q    = idx & 15;
        const int c4   = q * 4;
        const short* rp = xbc + (row0 + trow) * CONVDIM;
        const short4 xv = *(const short4*)(rp + h * 64 + c4);
        const short4 bv = *(const short4*)(rp + DINNER + c4);
        const float w = wsh[trow];
        XT[(0 * 16 + q) * LSTR + trow] = xv.x;
        XT[(1 * 16 + q) * LSTR + trow] = xv.y;
        XT[(2 * 16 + q) * LSTR + trow] = xv.z;
        XT[(3 * 16 + q) * LSTR + trow] = xv.w;
        BT[(0 * 16 + q) * LSTR + trow] = f2bf(bf2f(bv.x) * w);
        BT[(1 * 16 + q) * LSTR + trow] = f2bf(bf2f(bv.y) * w);
        BT[(2 * 16 + q) * LSTR + trow] = f2bf(bf2f(bv.z) * w);
        BT[(3 * 16 + q) * LSTR + trow] = f2bf(bf2f(bv.w) * w);
    }
    __syncthreads();

    f32x4 acc[4];
#pragma unroll
    for (int n = 0; n < 4; ++n) acc[n] = (f32x4)0.f;
#pragma unroll
    for (int ks = 0; ks < 2; ++ks) {
        const bf16x8 af = *(const bf16x8*)(XT + (wid * 16 + (lane & 15)) * LSTR + ks * 32 + (lane >> 4) * 8);
#pragma unroll
        for (int n = 0; n < 4; ++n) {
            const bf16x8 bfv = *(const bf16x8*)(BT + (n * 16 + (lane & 15)) * LSTR + ks * 32 + (lane >> 4) * 8);
            acc[n] = __builtin_amdgcn_mfma_f32_16x16x32_bf16(af, bfv, acc[n], 0, 0, 0);
        }
    }
    short* lp = lstate + ((size_t)bhc << 12);
    const int hi = lane >> 4;
    const int ncol = (lane & 15) * 4;
#pragma unroll
    for (int reg = 0; reg < 4; ++reg) {
        const int p = 16 * hi + 4 * reg + wid;
        short4 o;
        o.x = f2bf(acc[0][reg]); o.y = f2bf(acc[1][reg]);
        o.z = f2bf(acc[2][reg]); o.w = f2bf(acc[3][reg]);
        *(short4*)(lp + p * 64 + ncol) = o;
    }
}

// ---------------- scan pass 2: inter-chunk recurrence, short4-wide ----------
__global__ __launch_bounds__(256) void state_prefix_kernel(short* __restrict__ lstate,
                                                           const float* __restrict__ decayC) {
    const int idx = blockIdx.x * 256 + threadIdx.x;
    const int bh  = idx >> 10;
    const int pn4 = (idx & 1023) * 4;
    float S0 = 0.f, S1 = 0.f, S2 = 0.f, S3 = 0.f;
    for (int c = 0; c < NCHUNK; ++c) {
        short4* ptr = (short4*)(lstate + (((size_t)bh * NCHUNK + c) << 12) + pn4);
        const short4 l4 = *ptr;
        short4 o;
        o.x = f2bf(S0); o.y = f2bf(S1); o.z = f2bf(S2); o.w = f2bf(S3);
        *ptr = o;
        const float d = decayC[bh * NCHUNK + c];
        S0 = fmaf(S0, d, bf2f(l4.x));
        S1 = fmaf(S1, d, bf2f(l4.y));
        S2 = fmaf(S2, d, bf2f(l4.z));
        S3 = fmaf(S3, d, bf2f(l4.w));
    }
}

// ---- scan pass 3 (MFMA): y = mask(C@B^T)@X + exp(cum)*(C@SP^T) + Dp*X, fused gating.
// XOR-swizzled [64][64] tiles (no pad) -> LDS 32768 B exactly -> 5 blocks/CU.
// cums/dt in per-wave registers (redundant 64-lane prefix), fetched via dynamic shfl. ----
__global__ __launch_bounds__(256) void chunk_scan_mfma(const float* __restrict__ dt,
                                                       short* __restrict__ xbc,
                                                       const short* __restrict__ zxb,
                                                       float* __restrict__ rowss,
                                                       const float* __restrict__ dt_bias,
                                                       const float* __restrict__ A_log,
                                                       const float* __restrict__ Dp,
                                                       const short* __restrict__ lstate) {
    const int bhc = blockIdx.x;
    const int c = bhc & (NCHUNK - 1), bh = bhc >> 6, h = bh & (NHEADS - 1), b = bh >> 3;
    const int tid = threadIdx.x, lane = tid & 63, wid = tid >> 6;
    __shared__ short BsMs[64 * 64]; // B rows [t][n]; later masked scores [s][t]
    __shared__ short Cs[64 * 64];   // C rows [s][n]
    __shared__ short XT[64 * 64];   // X^T, slot-permuted
    __shared__ short SP[64 * 64];   // prefix state, slot-permuted
    short* Bs = BsMs;
    short* Ms = BsMs;
    const size_t row0 = (size_t)b * SEQ + (size_t)c * CHUNK;

    // per-wave redundant fp32 prefix of aneg*dt (identical across waves)
    const float aneg  = -__expf(A_log[h]);
    const float dbias = dt_bias[h];
    const float draw = dt[(row0 + lane) * NHEADS + h] + dbias;
    const float dtv  = (draw > 20.f) ? draw : log1pf(__expf(draw));
    float cum = aneg * dtv;
#pragma unroll
    for (int off = 1; off < 64; off <<= 1) {
        const float nv = __shfl_up(cum, off);
        if (lane >= off) cum += nv;
    }

#pragma unroll
    for (int r = 0; r < 4; ++r) {
        const int idx  = tid + r * 256;
        const int trow = idx >> 4;
        const int q    = idx & 15;
        const int c4   = q * 4;
        const short* rp = xbc + (row0 + trow) * CONVDIM;
        const short4 xv = *(const short4*)(rp + h * 64 + c4);
        const int hoff = ((((q >> 1) ^ trow) & 7) << 3) + (q & 1) * 4;
        *(short4*)(Bs + trow * 64 + hoff) = *(const short4*)(rp + DINNER + c4);
        *(short4*)(Cs + trow * 64 + hoff) = *(const short4*)(rp + DINNER + DSTATE + c4);
        // p-row c4+i -> slot (i*16 + q), column trow (swizzled)
        XT[swz(0 * 16 + q, trow)] = xv.x;
        XT[swz(1 * 16 + q, trow)] = xv.y;
        XT[swz(2 * 16 + q, trow)] = xv.z;
        XT[swz(3 * 16 + q, trow)] = xv.w;
    }
#pragma unroll
    for (int r = 0; r < 4; ++r) {
        const int idx = tid + r * 256;
        const int p = idx >> 4, q = idx & 15;
        const int pslot = ((p & 3) << 4) | (p >> 2);
        const int hoff = ((((q >> 1) ^ pslot) & 7) << 3) + (q & 1) * 4;
        *(short4*)(SP + pslot * 64 + hoff) =
            *(const short4*)(lstate + ((size_t)bhc << 12) + p * 64 + q * 4);
    }
    __syncthreads();

    // G = C @ B^T (over n)
    f32x4 accG[4];
#pragma unroll
    for (int tf = 0; tf < 4; ++tf) accG[tf] = (f32x4)0.f;
    __builtin_amdgcn_s_setprio(1);
#pragma unroll
    for (int ks = 0; ks < 2; ++ks) {
        const int crow = wid * 16 + (lane & 15);
        const bf16x8 af = *(const bf16x8*)(Cs + crow * 64 + (((ks * 4 + (lane >> 4)) ^ crow) & 7) * 8);
#pragma unroll
        for (int tf = 0; tf < 4; ++tf) {
            const int brw = tf * 16 + (lane & 15);
            const bf16x8 bfv = *(const bf16x8*)(Bs + brw * 64 + (((ks * 4 + (lane >> 4)) ^ brw) & 7) * 8);
            accG[tf] = __builtin_amdgcn_mfma_f32_16x16x32_bf16(af, bfv, accG[tf], 0, 0, 0);
        }
    }
    __builtin_amdgcn_s_setprio(0);
    __syncthreads();   // all waves done reading Bs before Ms overlays it

    // causal mask + decay scale -> Ms (bf16), overlaid on Bs
    const int srow0 = wid * 16 + (lane >> 4) * 4;
    float csr[4];
#pragma unroll
    for (int reg = 0; reg < 4; ++reg) csr[reg] = __shfl(cum, srow0 + reg);
#pragma unroll
    for (int tf = 0; tf < 4; ++tf) {
        const int t = tf * 16 + (lane & 15);
        const float ct  = __shfl(cum, t);
        const float dtt = __shfl(dtv, t);
#pragma unroll
        for (int reg = 0; reg < 4; ++reg) {
            const int s = srow0 + reg;
            const float m = (t <= s) ? accG[tf][reg] * __expf(csr[reg] - ct) * dtt : 0.f;
            Ms[swz(s, t)] = f2bf(m);
        }
    }
    __syncthreads();

    // Y1 = M @ X ; Y2 = C @ SP^T  (B-operands slot-permuted: pos j of frag pf = p-row 4j+pf)
    f32x4 acc1[4], acc2[4];
#pragma unroll
    for (int pf = 0; pf < 4; ++pf) { acc1[pf] = (f32x4)0.f; acc2[pf] = (f32x4)0.f; }
    __builtin_amdgcn_s_setprio(1);
#pragma unroll
    for (int ks = 0; ks < 2; ++ks) {
        const int mrow = wid * 16 + (lane & 15);
        const int ch = ks * 4 + (lane >> 4);
        const bf16x8 am = *(const bf16x8*)(Ms + mrow * 64 + ((ch ^ mrow) & 7) * 8);
        const bf16x8 ac = *(const bf16x8*)(Cs + mrow * 64 + ((ch ^ mrow) & 7) * 8);
#pragma unroll
        for (int pf = 0; pf < 4; ++pf) {
            const int prow = pf * 16 + (lane & 15);
            const bf16x8 bx = *(const bf16x8*)(XT + prow * 64 + ((ch ^ prow) & 7) * 8);
            const bf16x8 bs = *(const bf16x8*)(SP + prow * 64 + ((ch ^ prow) & 7) * 8);
            acc1[pf] = __builtin_amdgcn_mfma_f32_16x16x32_bf16(am, bx, acc1[pf], 0, 0, 0);
            acc2[pf] = __builtin_amdgcn_mfma_f32_16x16x32_bf16(ac, bs, acc2[pf], 0, 0, 0);
        }
    }
    __builtin_amdgcn_s_setprio(0);
    const float dpv = Dp[h];
    float es[4];
#pragma unroll
    for (int reg = 0; reg < 4; ++reg) es[reg] = __expf(csr[reg]);
    const int j = lane & 15;
#pragma unroll
    for (int reg = 0; reg < 4; ++reg) {
        const int s = srow0 + reg;
        const short4 z4 = *(const short4*)(zxb + (row0 + s) * ZSTR + h * 64 + j * 4);
        short4 o;
        float ssq = 0.f;
#pragma unroll
        for (int pf = 0; pf < 4; ++pf) {
            const float xv = bf2f(XT[swz(pf * 16 + j, s)]);
            const float yv = acc1[pf][reg] + es[reg] * acc2[pf][reg] + dpv * xv;
            const float zf = bf2f(((const short*)&z4)[pf]);
            const float v  = yv * zf / (1.f + __expf(-zf));
            ((short*)&o)[pf] = f2bf(v);
            ssq = fmaf(v, v, ssq);
        }
        *(short4*)(xbc + (row0 + s) * CONVDIM + h * 64 + j * 4) = o;
        ssq += __shfl_xor(ssq, 1);
        ssq += __shfl_xor(ssq, 2);
        ssq += __shfl_xor(ssq, 4);
        ssq += __shfl_xor(ssq, 8);
        if (j == 0) rowss[(row0 + s) * NHEADS + h] = ssq;
    }
}

// ---------------- launch ----------------
extern "C" void kernel_launch(void* const* d_in, const int* in_sizes, int n_in,
                              void* d_out, int out_size, void* d_ws, size_t ws_size,
                              hipStream_t stream) {
    (void)in_sizes; (void)n_in; (void)out_size; (void)d_ws; (void)ws_size;
    const float* x      = (const float*)d_in[0];
    const float* W_in   = (const float*)d_in[1];
    const float* conv_w = (const float*)d_in[2];
    const float* conv_b = (const float*)d_in[3];
    const float* dt_b   = (const float*)d_in[4];
    const float* A_log  = (const float*)d_in[5];
    const float* Dp     = (const float*)d_in[6];
    const float* g_w    = (const float*)d_in[7];
    const float* n_w    = (const float*)d_in[8];
    const float* W_out  = (const float*)d_in[9];
    float* out = (float*)d_out;

    short *xn, *zxb, *xbc, *winb, *woutb, *lst;
    float *dtv, *dcy, *rss;
    hipGetSymbolAddress((void**)&xn,    HIP_SYMBOL(g_xn));
    hipGetSymbolAddress((void**)&zxb,   HIP_SYMBOL(g_zxb));
    hipGetSymbolAddress((void**)&xbc,   HIP_SYMBOL(g_xbc));
    hipGetSymbolAddress((void**)&dtv,   HIP_SYMBOL(g_dt));
    hipGetSymbolAddress((void**)&rss,   HIP_SYMBOL(g_rowss));
    hipGetSymbolAddress((void**)&lst,   HIP_SYMBOL(g_lstate));
    hipGetSymbolAddress((void**)&dcy,   HIP_SYMBOL(g_decayC));
    hipGetSymbolAddress((void**)&winb,  HIP_SYMBOL(g_Winb));
    hipGetSymbolAddress((void**)&woutb, HIP_SYMBOL(g_Woutb));

    convert_bf16_kernel<<<(ZSTR * DMODEL) / 256, 256, 0, stream>>>(
        W_in, winb, ZSTR * DMODEL, ZSTR * DMODEL);
    convert_wout_kernel<<<(DMODEL * DINNER) / 256, 256, 0, stream>>>(W_out, g_w, woutb);

    rmsnorm_dt_kernel<<<NROWS / 4, 256, 0, stream>>>(x, n_w, W_in, xn, dtv);

    gemm_bf16_nt<false, short><<<(ZSTR / 128) * (NROWS / 128), 256, 0, stream>>>(
        xn, winb, nullptr, nullptr, zxb, ZSTR / 128, NROWS, ZSTR, DMODEL, DMODEL);

    conv_silu_kernel<<<(NROWS / 8 * 80) / 256, 256, 0, stream>>>(zxb, conv_w, conv_b, xbc);

    chunk_state_mfma<<<BATCH * NHEADS * NCHUNK, 256, 0, stream>>>(dtv, xbc, dt_b, A_log, lst, dcy);
    state_prefix_kernel<<<(BATCH * NHEADS * HEADDIM * DSTATE) / (4 * 256), 256, 0, stream>>>(lst, dcy);
    chunk_scan_mfma<<<BATCH * NHEADS * NCHUNK, 256, 0, stream>>>(
        dtv, xbc, zxb, rss, dt_b, A_log, Dp, lst);

    gemm_bf16_nt<true, float><<<(DMODEL / 128) * (NROWS / 128), 256, 0, stream>>>(
        xbc, woutb, x, rss, out, DMODEL / 128, NROWS, DMODEL, DINNER, CONVDIM);
}